// Round 4
// baseline (350.265 us; speedup 1.0000x reference)
//
#include <hip/hip_runtime.h>

#define NEG_SLOPE 0.2f

__device__ __forceinline__ float elu1(float v) { return v > 0.f ? v : expm1f(v); }
__device__ __forceinline__ float lrelu(float v) { return v > 0.f ? v : NEG_SLOPE * v; }

// ---------------- CSR build via bucketed counting sort ----------------
// Buckets of 64 consecutive dst ids. NBUCK = ceil(N/64). CAP per bucket
// sized for uniform-random dst (mean 1087, sigma 33 at E=800K,N=50K).

#define BSHIFT 6
#define BCAP 1536

// bin edges into buckets: pairs[b*CAP + rank] = (src, dst)
__global__ __launch_bounds__(256) void k_binA(
    const int* __restrict__ ei, int E, int ET,
    int* __restrict__ bcnt, uint2* __restrict__ pairs) {
    int e = blockIdx.x * 256 + threadIdx.x;
    if (e >= ET) return;
    int s, d;
    if (e < E) { s = ei[e]; d = ei[E + e]; } else { s = d = e - E; }
    int b = d >> BSHIFT;
    int p = atomicAdd(bcnt + b, 1);
    pairs[(size_t)b * BCAP + p] = make_uint2((unsigned)s, (unsigned)d);
}

// exclusive scan of bucket counts (nb <= 1024, single block)
__global__ __launch_bounds__(1024) void k_bscan(
    const int* __restrict__ bcnt, int* __restrict__ bbase,
    int* __restrict__ off, int nb, int N, int ET) {
    __shared__ int ws16[16];
    int i = threadIdx.x, lane = i & 63, w = i >> 6;
    int v = (i < nb) ? bcnt[i] : 0, sc = v;
#pragma unroll
    for (int m = 1; m < 64; m <<= 1) {
        int t = __shfl_up(sc, m, 64);
        if (lane >= m) sc += t;
    }
    if (lane == 63) ws16[w] = sc;
    __syncthreads();
    if (w == 0 && lane < 16) {
        int s2 = ws16[lane];
#pragma unroll
        for (int m = 1; m < 16; m <<= 1) {
            int t = __shfl_up(s2, m, 16);
            if (lane >= m) s2 += t;
        }
        ws16[lane] = s2;
    }
    __syncthreads();
    int carry = (w == 0) ? 0 : ws16[w - 1];
    if (i < nb) bbase[i] = carry + sc - v;   // exclusive
    if (i == 0) off[N] = ET;
}

// per-bucket LDS counting sort: emits off[] for its 64 dsts and csr_src slice
__global__ __launch_bounds__(256) void k_sortB(
    const uint2* __restrict__ pairs, const int* __restrict__ bcnt,
    const int* __restrict__ bbase, int* __restrict__ off,
    int* __restrict__ csr_src, int N) {
    __shared__ int hist[64], cur[64];
    int b = blockIdx.x;
    int cnt = bcnt[b];
    int base = bbase[b];
    int dstBase = b << BSHIFT;
    const uint2* pb = pairs + (size_t)b * BCAP;
    if (threadIdx.x < 64) hist[threadIdx.x] = 0;
    __syncthreads();
    for (int i = threadIdx.x; i < cnt; i += 256)
        atomicAdd(&hist[pb[i].y - dstBase], 1);
    __syncthreads();
    if (threadIdx.x < 64) {
        int v = hist[threadIdx.x], sc = v;
#pragma unroll
        for (int m = 1; m < 64; m <<= 1) {
            int t = __shfl_up(sc, m, 64);
            if (threadIdx.x >= m) sc += t;
        }
        int ex = sc - v;
        cur[threadIdx.x] = ex;
        int d = dstBase + threadIdx.x;
        if (d < N) off[d] = base + ex;
    }
    __syncthreads();
    for (int i = threadIdx.x; i < cnt; i += 256) {
        uint2 pr = pb[i];
        int r = atomicAdd(&cur[pr.y - dstBase], 1);
        csr_src[base + r] = (int)pr.x;
    }
}

// ---------------- layer 1 (aggregate in 5-dim input space) ----------------

__global__ __launch_bounds__(256) void k_attn1(
    const float* __restrict__ x, const float* __restrict__ W1,
    const float* __restrict__ att_s, const float* __restrict__ att_d,
    float* __restrict__ x8, float4* __restrict__ as4, float4* __restrict__ ad4, int N) {
    __shared__ float Ps[5][4], Pd[5][4];
    if (threadIdx.x < 40) {
        int pair = threadIdx.x & 1, idx = threadIdx.x >> 1;
        int k = idx >> 2, h = idx & 3;
        const float* att = pair ? att_d : att_s;
        float r = 0.f;
#pragma unroll
        for (int c = 0; c < 32; ++c) r = fmaf(W1[k * 128 + h * 32 + c], att[h * 32 + c], r);
        if (pair) Pd[k][h] = r; else Ps[k][h] = r;
    }
    __syncthreads();
    int n = blockIdx.x * 256 + threadIdx.x;
    if (n >= N) return;
    float xv[5];
#pragma unroll
    for (int k = 0; k < 5; ++k) xv[k] = x[(size_t)n * 5 + k];
#pragma unroll
    for (int k = 0; k < 5; ++k) x8[(size_t)n * 8 + k] = xv[k];
    float s0 = 0, s1 = 0, s2 = 0, s3 = 0, d0 = 0, d1 = 0, d2 = 0, d3 = 0;
#pragma unroll
    for (int k = 0; k < 5; ++k) {
        s0 = fmaf(xv[k], Ps[k][0], s0); s1 = fmaf(xv[k], Ps[k][1], s1);
        s2 = fmaf(xv[k], Ps[k][2], s2); s3 = fmaf(xv[k], Ps[k][3], s3);
        d0 = fmaf(xv[k], Pd[k][0], d0); d1 = fmaf(xv[k], Pd[k][1], d1);
        d2 = fmaf(xv[k], Pd[k][2], d2); d3 = fmaf(xv[k], Pd[k][3], d3);
    }
    as4[n] = make_float4(s0, s1, s2, s3);
    ad4[n] = make_float4(d0, d1, d2, d3);
}

// 16-lane group per dst: single-pass softmax-weighted aggregation of x
__global__ __launch_bounds__(256) void k_agg1x(
    const int* __restrict__ off, const int* __restrict__ csr_src,
    const float4* __restrict__ as4, const float4* __restrict__ ad4,
    const float* __restrict__ x8, float* __restrict__ aggx, int N) {
    int g = (blockIdx.x * 256 + threadIdx.x) >> 4;
    int lane = threadIdx.x & 15;
    if (g >= N) return;
    int p0 = off[g], p1 = off[g + 1];
    float4 ad = ad4[g];
    float den0 = 0, den1 = 0, den2 = 0, den3 = 0;
    float acc[4][5] = {};
    for (int p = p0 + lane; p < p1; p += 16) {
        int s = csr_src[p];
        float4 as = as4[s];
        float v0 = __expf(lrelu(as.x + ad.x));
        float v1 = __expf(lrelu(as.y + ad.y));
        float v2 = __expf(lrelu(as.z + ad.z));
        float v3 = __expf(lrelu(as.w + ad.w));
        den0 += v0; den1 += v1; den2 += v2; den3 += v3;
        const float* xr = x8 + (size_t)s * 8;
        float4 xlo = *(const float4*)xr;
        float x4 = xr[4];
        float xk[5] = {xlo.x, xlo.y, xlo.z, xlo.w, x4};
#pragma unroll
        for (int k = 0; k < 5; ++k) {
            acc[0][k] = fmaf(v0, xk[k], acc[0][k]);
            acc[1][k] = fmaf(v1, xk[k], acc[1][k]);
            acc[2][k] = fmaf(v2, xk[k], acc[2][k]);
            acc[3][k] = fmaf(v3, xk[k], acc[3][k]);
        }
    }
#pragma unroll
    for (int m = 8; m; m >>= 1) {
        den0 += __shfl_xor(den0, m, 16); den1 += __shfl_xor(den1, m, 16);
        den2 += __shfl_xor(den2, m, 16); den3 += __shfl_xor(den3, m, 16);
#pragma unroll
        for (int h = 0; h < 4; ++h)
#pragma unroll
            for (int k = 0; k < 5; ++k) acc[h][k] += __shfl_xor(acc[h][k], m, 16);
    }
    if (lane == 0) {
        float i0 = 1.f / den0, i1 = 1.f / den1, i2 = 1.f / den2, i3 = 1.f / den3;
        float4* o = (float4*)(aggx + (size_t)g * 20);
        o[0] = make_float4(acc[0][0] * i0, acc[0][1] * i0, acc[0][2] * i0, acc[0][3] * i0);
        o[1] = make_float4(acc[0][4] * i0, acc[1][0] * i1, acc[1][1] * i1, acc[1][2] * i1);
        o[2] = make_float4(acc[1][3] * i1, acc[1][4] * i1, acc[2][0] * i2, acc[2][1] * i2);
        o[3] = make_float4(acc[2][2] * i2, acc[2][3] * i2, acc[2][4] * i2, acc[3][0] * i3);
        o[4] = make_float4(acc[3][1] * i3, acc[3][2] * i3, acc[3][3] * i3, acc[3][4] * i3);
    }
}

// out1 = elu(aggx @ W1 + b1)
__global__ __launch_bounds__(256) void k_expand1(
    const float* __restrict__ aggx, const float* __restrict__ W1,
    const float* __restrict__ b1, float* __restrict__ out1, int N) {
    __shared__ float Wl[5 * 128];
    for (int i = threadIdx.x; i < 5 * 128; i += 256) Wl[i] = W1[i];
    __syncthreads();
    int t = blockIdx.x * 256 + threadIdx.x;
    int n = t >> 7, c = t & 127;
    if (n >= N) return;
    int h = c >> 5;
    const float* ag = aggx + (size_t)n * 20 + h * 5;
    float r = b1[c];
#pragma unroll
    for (int k = 0; k < 5; ++k) r = fmaf(ag[k], Wl[k * 128 + c], r);
    out1[(size_t)n * 128 + c] = elu1(r);
}

// ---------------- layer 2 ----------------

__global__ __launch_bounds__(256) void k_feat2(
    const float* __restrict__ h1b, const float* __restrict__ W2,
    const float* __restrict__ att_s, const float* __restrict__ att_d,
    float* __restrict__ h2, float* __restrict__ a_s, float* __restrict__ a_d, int N) {
    __shared__ float Wl[128 * 32];
    for (int i = threadIdx.x; i < 128 * 32; i += 256) Wl[i] = W2[i];
    __syncthreads();
    int t = blockIdx.x * 256 + threadIdx.x;
    int n = t >> 5, c = t & 31;
    if (n >= N) return;
    const float4* hr4 = (const float4*)(h1b + (size_t)n * 128);
    float acc = 0.f;
#pragma unroll
    for (int k4 = 0; k4 < 32; ++k4) {
        float4 hv = hr4[k4];
        acc = fmaf(hv.x, Wl[(k4 * 4 + 0) * 32 + c], acc);
        acc = fmaf(hv.y, Wl[(k4 * 4 + 1) * 32 + c], acc);
        acc = fmaf(hv.z, Wl[(k4 * 4 + 2) * 32 + c], acc);
        acc = fmaf(hv.w, Wl[(k4 * 4 + 3) * 32 + c], acc);
    }
    h2[(size_t)n * 32 + c] = acc;
    float as = acc * att_s[c], ad = acc * att_d[c];
#pragma unroll
    for (int m = 16; m; m >>= 1) {
        as += __shfl_xor(as, m, 32);
        ad += __shfl_xor(ad, m, 32);
    }
    if (c == 0) { a_s[n] = as; a_d[n] = ad; }
}

// 32-lane group per dst: single-pass aggregation + bias/ELU + fused MLP head
__global__ __launch_bounds__(256) void k_agg2h(
    const int* __restrict__ off, const int* __restrict__ csr_src,
    const float* __restrict__ a_s, const float* __restrict__ a_d,
    const float* __restrict__ h2, const float* __restrict__ b2,
    const float* __restrict__ Wc1, const float* __restrict__ bc1,
    const float* __restrict__ Wc2, const float* __restrict__ bc2,
    float* __restrict__ out, int N) {
    __shared__ float Wl[512];
    __shared__ float b2l[32], b1l[16], w2l[16];
    for (int i = threadIdx.x; i < 512; i += 256) Wl[i] = Wc1[i];
    if (threadIdx.x < 32) b2l[threadIdx.x] = b2[threadIdx.x];
    if (threadIdx.x < 16) {
        b1l[threadIdx.x] = bc1[threadIdx.x];
        w2l[threadIdx.x] = Wc2[threadIdx.x];
    }
    __syncthreads();
    int g = (blockIdx.x * 256 + threadIdx.x) >> 5;
    int lane = threadIdx.x & 31;
    if (g >= N) return;
    int p0 = off[g], p1 = off[g + 1];
    float ad = a_d[g];
    float acc = 0.f, den = 0.f;
    int p = p0;
    for (; p + 1 < p1; p += 2) {
        int s0 = csr_src[p], s1 = csr_src[p + 1];
        float e0 = a_s[s0], e1 = a_s[s1];
        float g0 = h2[(size_t)s0 * 32 + lane], g1 = h2[(size_t)s1 * 32 + lane];
        float v0 = __expf(lrelu(e0 + ad)), v1 = __expf(lrelu(e1 + ad));
        den += v0 + v1;
        acc = fmaf(v0, g0, acc);
        acc = fmaf(v1, g1, acc);
    }
    if (p < p1) {
        int s0 = csr_src[p];
        float v0 = __expf(lrelu(a_s[s0] + ad));
        den += v0;
        acc = fmaf(v0, h2[(size_t)s0 * 32 + lane], acc);
    }
    float z = elu1(fmaf(acc, 1.f / den, b2l[lane]));
    float y = b1l[lane & 15];
#pragma unroll
    for (int c = 0; c < 32; ++c) {
        float zc = __shfl(z, c, 32);
        y = fmaf(zc, Wl[c * 16 + (lane & 15)], y);
    }
    y = fmaxf(y, 0.f);
    float t = (lane < 16) ? y * w2l[lane] : 0.f;
#pragma unroll
    for (int m = 8; m; m >>= 1) t += __shfl_xor(t, m, 32);
    if (lane == 0) out[g] = t + bc2[0];
}

extern "C" void kernel_launch(void* const* d_in, const int* in_sizes, int n_in,
                              void* d_out, int out_size, void* d_ws, size_t ws_size,
                              hipStream_t stream) {
    const float* x   = (const float*)d_in[0];
    const int*   ei  = (const int*)d_in[1];
    const float* W1  = (const float*)d_in[2];
    const float* as1 = (const float*)d_in[3];
    const float* ad1 = (const float*)d_in[4];
    const float* b1  = (const float*)d_in[5];
    const float* W2  = (const float*)d_in[6];
    const float* as2 = (const float*)d_in[7];
    const float* ad2 = (const float*)d_in[8];
    const float* b2  = (const float*)d_in[9];
    const float* Wc1 = (const float*)d_in[10];
    const float* bc1 = (const float*)d_in[11];
    const float* Wc2 = (const float*)d_in[12];
    const float* bc2 = (const float*)d_in[13];
    float* out = (float*)d_out;

    const int N = out_size;                 // 50000
    const int E = in_sizes[1] / 2;          // 800000
    const int ET = E + N;                   // + self loops
    const int NBUCK = (N + 63) >> BSHIFT;   // 782

    // Workspace layout
    float*  ws    = (float*)d_ws;
    float*  out1  = ws;                               // N*128
    float*  h2    = out1 + (size_t)N * 128;           // N*32
    float*  x8    = h2   + (size_t)N * 32;            // N*8
    float4* as4   = (float4*)(x8 + (size_t)N * 8);    // N float4
    float4* ad4   = as4 + N;                          // N float4
    float*  aggx  = (float*)(ad4 + N);                // N*20
    float*  a_s2  = aggx + (size_t)N * 20;            // N
    float*  a_d2  = a_s2 + N;                         // N
    int*    off   = (int*)(a_d2 + N);                 // N+1
    int*    csr_src = off + (N + 2);                  // ET
    int*    bcnt  = csr_src + ET;                     // NBUCK
    int*    bbase = bcnt + NBUCK;                     // NBUCK
    // align pairs to 8B
    size_t  poff  = ((size_t)(bbase + NBUCK) + 7) & ~(size_t)7;
    uint2*  pairs = (uint2*)poff;                     // NBUCK*BCAP uint2 (9.6 MB)

    auto cdiv = [](long long a, long long b) { return (int)((a + b - 1) / b); };
    const int B = 256;

    // ---- CSR build (bucketed counting sort) ----
    hipMemsetAsync(bcnt, 0, (size_t)NBUCK * sizeof(int), stream);
    k_binA<<<cdiv(ET, B), B, 0, stream>>>(ei, E, ET, bcnt, pairs);
    k_bscan<<<1, 1024, 0, stream>>>(bcnt, bbase, off, NBUCK, N, ET);
    k_sortB<<<NBUCK, B, 0, stream>>>(pairs, bcnt, bbase, off, csr_src, N);

    // ---- layer 1 (input-space aggregation) ----
    k_attn1<<<cdiv(N, B), B, 0, stream>>>(x, W1, as1, ad1, x8, as4, ad4, N);
    k_agg1x<<<cdiv((long long)N * 16, B), B, 0, stream>>>(off, csr_src, as4, ad4, x8, aggx, N);
    k_expand1<<<cdiv((long long)N * 128, B), B, 0, stream>>>(aggx, W1, b1, out1, N);

    // ---- layer 2 ----
    k_feat2<<<cdiv((long long)N * 32, B), B, 0, stream>>>(out1, W2, as2, ad2, h2, a_s2, a_d2, N);
    k_agg2h<<<cdiv((long long)N * 32, B), B, 0, stream>>>(off, csr_src, a_s2, a_d2, h2, b2,
                                                          Wc1, bc1, Wc2, bc2, out, N);
}

// Round 5
// 175.440 us; speedup vs baseline: 1.9965x; 1.9965x over previous
//
#include <hip/hip_runtime.h>

#define NEG_SLOPE 0.2f
#define BSHIFT 6          // bucket = 64 consecutive dst ids
#define SCATB 64          // blocks in count/scatter phases

__device__ __forceinline__ float elu1(float v) { return v > 0.f ? v : expm1f(v); }
__device__ __forceinline__ float lrelu(float v) { return v > 0.f ? v : NEG_SLOPE * v; }

// ---------------- CSR build: exact-offset bucketing (no global atomics) ----------------

// Phase 1: per-block LDS histogram over buckets -> Cmat[bucket*SCATB + block]
__global__ __launch_bounds__(256) void k_cnt(
    const int* __restrict__ ei, int E, int ET, int chunk,
    int* __restrict__ Cmat, int nbuck) {
    __shared__ int hist[784];
    for (int i = threadIdx.x; i < nbuck; i += 256) hist[i] = 0;
    __syncthreads();
    int k = blockIdx.x;
    int e0 = k * chunk, e1 = min(e0 + chunk, ET);
    for (int e = e0 + threadIdx.x; e < e1; e += 256) {
        int d = (e < E) ? ei[E + e] : e - E;
        atomicAdd(&hist[d >> BSHIFT], 1);
    }
    __syncthreads();
    for (int i = threadIdx.x; i < nbuck; i += 256)
        Cmat[i * SCATB + k] = hist[i];
}

// Phase 2a: per-block inclusive scan of Cmat -> blkoff[i+1], block totals -> bsum
__global__ __launch_bounds__(256) void k_scan1(
    const int* __restrict__ Cmat, int* __restrict__ blkoff, int* __restrict__ bsum, int M) {
    __shared__ int ws4[4], wsoff[4];
    int i = blockIdx.x * 256 + threadIdx.x;
    int lane = threadIdx.x & 63, w = threadIdx.x >> 6;
    int v = (i < M) ? Cmat[i] : 0;
    int sc = v;
#pragma unroll
    for (int m = 1; m < 64; m <<= 1) {
        int t = __shfl_up(sc, m, 64);
        if (lane >= m) sc += t;
    }
    if (lane == 63) ws4[w] = sc;
    __syncthreads();
    if (threadIdx.x == 0) {
        int r = 0;
#pragma unroll
        for (int j = 0; j < 4; ++j) { wsoff[j] = r; r += ws4[j]; }
        bsum[blockIdx.x] = r;
    }
    __syncthreads();
    if (i < M) blkoff[i + 1] = sc + wsoff[w];
}

// Phase 2b: scan block totals (nb <= 256)
__global__ __launch_bounds__(256) void k_scan2(int* __restrict__ bsum, int nb) {
    __shared__ int ws4[4], wsoff[4];
    int i = threadIdx.x;
    int lane = i & 63, w = i >> 6;
    int v = (i < nb) ? bsum[i] : 0;
    int sc = v;
#pragma unroll
    for (int m = 1; m < 64; m <<= 1) {
        int t = __shfl_up(sc, m, 64);
        if (lane >= m) sc += t;
    }
    if (lane == 63) ws4[w] = sc;
    __syncthreads();
    if (i == 0) {
        int r = 0;
#pragma unroll
        for (int j = 0; j < 4; ++j) { wsoff[j] = r; r += ws4[j]; }
    }
    __syncthreads();
    if (i < nb) bsum[i] = sc + wsoff[w];
}

// Phase 2c: add block offsets; init blkoff[0], off[N]
__global__ __launch_bounds__(256) void k_scan3(
    int* __restrict__ blkoff, const int* __restrict__ bsum,
    int* __restrict__ off, int M, int N, int ET) {
    int i = blockIdx.x * 256 + threadIdx.x;
    if (i == 0) { blkoff[0] = 0; off[N] = ET; }
    if (i >= M) return;
    if (blockIdx.x > 0) blkoff[i + 1] += bsum[blockIdx.x - 1];
}

// Phase 3: re-bin edges, write packed pairs at exact offsets (LDS cursors, no global atomics)
__global__ __launch_bounds__(256) void k_scat(
    const int* __restrict__ ei, int E, int ET, int chunk,
    const int* __restrict__ blkoff, unsigned* __restrict__ pairs, int nbuck) {
    __shared__ int cur[784];
    int k = blockIdx.x;
    for (int i = threadIdx.x; i < nbuck; i += 256)
        cur[i] = blkoff[i * SCATB + k];
    __syncthreads();
    int e0 = k * chunk, e1 = min(e0 + chunk, ET);
    for (int e = e0 + threadIdx.x; e < e1; e += 256) {
        int s, d;
        if (e < E) { s = ei[e]; d = ei[E + e]; } else { s = d = e - E; }
        int p = atomicAdd(&cur[d >> BSHIFT], 1);
        pairs[p] = (unsigned)s | ((unsigned)(d & 63) << 16);   // src < 65536
    }
}

// Phase 4: per-bucket LDS counting sort -> off[] and csr_src (contiguous I/O)
__global__ __launch_bounds__(256) void k_sortB(
    const unsigned* __restrict__ pairs, const int* __restrict__ blkoff,
    int* __restrict__ off, int* __restrict__ csr_src, int N, int ET, int nbuck) {
    __shared__ int hist[64], cur[64];
    int b = blockIdx.x;
    int base = blkoff[b * SCATB];
    int end  = (b + 1 < nbuck) ? blkoff[(b + 1) * SCATB] : ET;
    int cnt = end - base;
    int dstBase = b << BSHIFT;
    if (threadIdx.x < 64) hist[threadIdx.x] = 0;
    __syncthreads();
    for (int i = threadIdx.x; i < cnt; i += 256)
        atomicAdd(&hist[pairs[base + i] >> 16], 1);
    __syncthreads();
    if (threadIdx.x < 64) {
        int v = hist[threadIdx.x], sc = v;
#pragma unroll
        for (int m = 1; m < 64; m <<= 1) {
            int t = __shfl_up(sc, m, 64);
            if (threadIdx.x >= m) sc += t;
        }
        int ex = sc - v;
        cur[threadIdx.x] = ex;
        int d = dstBase + threadIdx.x;
        if (d < N) off[d] = base + ex;
    }
    __syncthreads();
    for (int i = threadIdx.x; i < cnt; i += 256) {
        unsigned pr = pairs[base + i];
        int r = atomicAdd(&cur[pr >> 16], 1);
        csr_src[base + r] = (int)(pr & 0xFFFFu);
    }
}

// ---------------- layer 1 (aggregate in 5-dim input space) ----------------

__global__ __launch_bounds__(256) void k_attn1(
    const float* __restrict__ x, const float* __restrict__ W1,
    const float* __restrict__ att_s, const float* __restrict__ att_d,
    float* __restrict__ x8, float4* __restrict__ as4, float4* __restrict__ ad4, int N) {
    __shared__ float Ps[5][4], Pd[5][4];
    if (threadIdx.x < 40) {
        int pair = threadIdx.x & 1, idx = threadIdx.x >> 1;
        int k = idx >> 2, h = idx & 3;
        const float* att = pair ? att_d : att_s;
        float r = 0.f;
#pragma unroll
        for (int c = 0; c < 32; ++c) r = fmaf(W1[k * 128 + h * 32 + c], att[h * 32 + c], r);
        if (pair) Pd[k][h] = r; else Ps[k][h] = r;
    }
    __syncthreads();
    int n = blockIdx.x * 256 + threadIdx.x;
    if (n >= N) return;
    float xv[5];
#pragma unroll
    for (int k = 0; k < 5; ++k) xv[k] = x[(size_t)n * 5 + k];
#pragma unroll
    for (int k = 0; k < 5; ++k) x8[(size_t)n * 8 + k] = xv[k];
    float s0 = 0, s1 = 0, s2 = 0, s3 = 0, d0 = 0, d1 = 0, d2 = 0, d3 = 0;
#pragma unroll
    for (int k = 0; k < 5; ++k) {
        s0 = fmaf(xv[k], Ps[k][0], s0); s1 = fmaf(xv[k], Ps[k][1], s1);
        s2 = fmaf(xv[k], Ps[k][2], s2); s3 = fmaf(xv[k], Ps[k][3], s3);
        d0 = fmaf(xv[k], Pd[k][0], d0); d1 = fmaf(xv[k], Pd[k][1], d1);
        d2 = fmaf(xv[k], Pd[k][2], d2); d3 = fmaf(xv[k], Pd[k][3], d3);
    }
    as4[n] = make_float4(s0, s1, s2, s3);
    ad4[n] = make_float4(d0, d1, d2, d3);
}

// 16-lane group per dst: single-pass softmax-weighted aggregation of x
__global__ __launch_bounds__(256) void k_agg1x(
    const int* __restrict__ off, const int* __restrict__ csr_src,
    const float4* __restrict__ as4, const float4* __restrict__ ad4,
    const float* __restrict__ x8, float* __restrict__ aggx, int N) {
    int g = (blockIdx.x * 256 + threadIdx.x) >> 4;
    int lane = threadIdx.x & 15;
    if (g >= N) return;
    int p0 = off[g], p1 = off[g + 1];
    float4 ad = ad4[g];
    float den0 = 0, den1 = 0, den2 = 0, den3 = 0;
    float acc[4][5] = {};
    for (int p = p0 + lane; p < p1; p += 16) {
        int s = csr_src[p];
        float4 as = as4[s];
        float v0 = __expf(lrelu(as.x + ad.x));
        float v1 = __expf(lrelu(as.y + ad.y));
        float v2 = __expf(lrelu(as.z + ad.z));
        float v3 = __expf(lrelu(as.w + ad.w));
        den0 += v0; den1 += v1; den2 += v2; den3 += v3;
        const float* xr = x8 + (size_t)s * 8;
        float4 xlo = *(const float4*)xr;
        float x4 = xr[4];
        float xk[5] = {xlo.x, xlo.y, xlo.z, xlo.w, x4};
#pragma unroll
        for (int k = 0; k < 5; ++k) {
            acc[0][k] = fmaf(v0, xk[k], acc[0][k]);
            acc[1][k] = fmaf(v1, xk[k], acc[1][k]);
            acc[2][k] = fmaf(v2, xk[k], acc[2][k]);
            acc[3][k] = fmaf(v3, xk[k], acc[3][k]);
        }
    }
#pragma unroll
    for (int m = 8; m; m >>= 1) {
        den0 += __shfl_xor(den0, m, 16); den1 += __shfl_xor(den1, m, 16);
        den2 += __shfl_xor(den2, m, 16); den3 += __shfl_xor(den3, m, 16);
#pragma unroll
        for (int h = 0; h < 4; ++h)
#pragma unroll
            for (int k = 0; k < 5; ++k) acc[h][k] += __shfl_xor(acc[h][k], m, 16);
    }
    if (lane == 0) {
        float i0 = 1.f / den0, i1 = 1.f / den1, i2 = 1.f / den2, i3 = 1.f / den3;
        float4* o = (float4*)(aggx + (size_t)g * 20);
        o[0] = make_float4(acc[0][0] * i0, acc[0][1] * i0, acc[0][2] * i0, acc[0][3] * i0);
        o[1] = make_float4(acc[0][4] * i0, acc[1][0] * i1, acc[1][1] * i1, acc[1][2] * i1);
        o[2] = make_float4(acc[1][3] * i1, acc[1][4] * i1, acc[2][0] * i2, acc[2][1] * i2);
        o[3] = make_float4(acc[2][2] * i2, acc[2][3] * i2, acc[2][4] * i2, acc[3][0] * i3);
        o[4] = make_float4(acc[3][1] * i3, acc[3][2] * i3, acc[3][3] * i3, acc[3][4] * i3);
    }
}

// out1 = elu(aggx @ W1 + b1)
__global__ __launch_bounds__(256) void k_expand1(
    const float* __restrict__ aggx, const float* __restrict__ W1,
    const float* __restrict__ b1, float* __restrict__ out1, int N) {
    __shared__ float Wl[5 * 128];
    for (int i = threadIdx.x; i < 5 * 128; i += 256) Wl[i] = W1[i];
    __syncthreads();
    int t = blockIdx.x * 256 + threadIdx.x;
    int n = t >> 7, c = t & 127;
    if (n >= N) return;
    int h = c >> 5;
    const float* ag = aggx + (size_t)n * 20 + h * 5;
    float r = b1[c];
#pragma unroll
    for (int k = 0; k < 5; ++k) r = fmaf(ag[k], Wl[k * 128 + c], r);
    out1[(size_t)n * 128 + c] = elu1(r);
}

// ---------------- layer 2 ----------------

__global__ __launch_bounds__(256) void k_feat2(
    const float* __restrict__ h1b, const float* __restrict__ W2,
    const float* __restrict__ att_s, const float* __restrict__ att_d,
    float* __restrict__ h2, float* __restrict__ a_s, float* __restrict__ a_d, int N) {
    __shared__ float Wl[128 * 32];
    for (int i = threadIdx.x; i < 128 * 32; i += 256) Wl[i] = W2[i];
    __syncthreads();
    int t = blockIdx.x * 256 + threadIdx.x;
    int n = t >> 5, c = t & 31;
    if (n >= N) return;
    const float4* hr4 = (const float4*)(h1b + (size_t)n * 128);
    float acc = 0.f;
#pragma unroll
    for (int k4 = 0; k4 < 32; ++k4) {
        float4 hv = hr4[k4];
        acc = fmaf(hv.x, Wl[(k4 * 4 + 0) * 32 + c], acc);
        acc = fmaf(hv.y, Wl[(k4 * 4 + 1) * 32 + c], acc);
        acc = fmaf(hv.z, Wl[(k4 * 4 + 2) * 32 + c], acc);
        acc = fmaf(hv.w, Wl[(k4 * 4 + 3) * 32 + c], acc);
    }
    h2[(size_t)n * 32 + c] = acc;
    float as = acc * att_s[c], ad = acc * att_d[c];
#pragma unroll
    for (int m = 16; m; m >>= 1) {
        as += __shfl_xor(as, m, 32);
        ad += __shfl_xor(ad, m, 32);
    }
    if (c == 0) { a_s[n] = as; a_d[n] = ad; }
}

// 32-lane group per dst: single-pass aggregation + bias/ELU + fused MLP head
__global__ __launch_bounds__(256) void k_agg2h(
    const int* __restrict__ off, const int* __restrict__ csr_src,
    const float* __restrict__ a_s, const float* __restrict__ a_d,
    const float* __restrict__ h2, const float* __restrict__ b2,
    const float* __restrict__ Wc1, const float* __restrict__ bc1,
    const float* __restrict__ Wc2, const float* __restrict__ bc2,
    float* __restrict__ out, int N) {
    __shared__ float Wl[512];
    __shared__ float b2l[32], b1l[16], w2l[16];
    for (int i = threadIdx.x; i < 512; i += 256) Wl[i] = Wc1[i];
    if (threadIdx.x < 32) b2l[threadIdx.x] = b2[threadIdx.x];
    if (threadIdx.x < 16) {
        b1l[threadIdx.x] = bc1[threadIdx.x];
        w2l[threadIdx.x] = Wc2[threadIdx.x];
    }
    __syncthreads();
    int g = (blockIdx.x * 256 + threadIdx.x) >> 5;
    int lane = threadIdx.x & 31;
    if (g >= N) return;
    int p0 = off[g], p1 = off[g + 1];
    float ad = a_d[g];
    float acc = 0.f, den = 0.f;
    int p = p0;
    for (; p + 1 < p1; p += 2) {
        int s0 = csr_src[p], s1 = csr_src[p + 1];
        float e0 = a_s[s0], e1 = a_s[s1];
        float g0 = h2[(size_t)s0 * 32 + lane], g1 = h2[(size_t)s1 * 32 + lane];
        float v0 = __expf(lrelu(e0 + ad)), v1 = __expf(lrelu(e1 + ad));
        den += v0 + v1;
        acc = fmaf(v0, g0, acc);
        acc = fmaf(v1, g1, acc);
    }
    if (p < p1) {
        int s0 = csr_src[p];
        float v0 = __expf(lrelu(a_s[s0] + ad));
        den += v0;
        acc = fmaf(v0, h2[(size_t)s0 * 32 + lane], acc);
    }
    float z = elu1(fmaf(acc, 1.f / den, b2l[lane]));
    float y = b1l[lane & 15];
#pragma unroll
    for (int c = 0; c < 32; ++c) {
        float zc = __shfl(z, c, 32);
        y = fmaf(zc, Wl[c * 16 + (lane & 15)], y);
    }
    y = fmaxf(y, 0.f);
    float t = (lane < 16) ? y * w2l[lane] : 0.f;
#pragma unroll
    for (int m = 8; m; m >>= 1) t += __shfl_xor(t, m, 32);
    if (lane == 0) out[g] = t + bc2[0];
}

extern "C" void kernel_launch(void* const* d_in, const int* in_sizes, int n_in,
                              void* d_out, int out_size, void* d_ws, size_t ws_size,
                              hipStream_t stream) {
    const float* x   = (const float*)d_in[0];
    const int*   ei  = (const int*)d_in[1];
    const float* W1  = (const float*)d_in[2];
    const float* as1 = (const float*)d_in[3];
    const float* ad1 = (const float*)d_in[4];
    const float* b1  = (const float*)d_in[5];
    const float* W2  = (const float*)d_in[6];
    const float* as2 = (const float*)d_in[7];
    const float* ad2 = (const float*)d_in[8];
    const float* b2  = (const float*)d_in[9];
    const float* Wc1 = (const float*)d_in[10];
    const float* bc1 = (const float*)d_in[11];
    const float* Wc2 = (const float*)d_in[12];
    const float* bc2 = (const float*)d_in[13];
    float* out = (float*)d_out;

    const int N = out_size;                  // 50000
    const int E = in_sizes[1] / 2;           // 800000
    const int ET = E + N;                    // + self loops
    const int nbuck = (N + 63) >> BSHIFT;    // 782
    const int M = nbuck * SCATB;             // 50048 scan elements
    const int chunk = (ET + SCATB - 1) / SCATB;

    // Workspace layout
    float*    ws    = (float*)d_ws;
    float*    out1  = ws;                               // N*128
    float*    h2    = out1 + (size_t)N * 128;           // N*32
    float*    x8    = h2   + (size_t)N * 32;            // N*8
    float4*   as4   = (float4*)(x8 + (size_t)N * 8);    // N float4
    float4*   ad4   = as4 + N;                          // N float4
    float*    aggx  = (float*)(ad4 + N);                // N*20
    float*    a_s2  = aggx + (size_t)N * 20;            // N
    float*    a_d2  = a_s2 + N;                         // N
    int*      off   = (int*)(a_d2 + N);                 // N+1
    int*      csr_src = off + (N + 2);                  // ET
    int*      Cmat  = csr_src + ET;                     // M
    int*      blkoff = Cmat + M;                        // M+1
    int*      bsum  = blkoff + (M + 2);                 // 256
    unsigned* pairs = (unsigned*)(bsum + 256);          // ET

    auto cdiv = [](long long a, long long b) { return (int)((a + b - 1) / b); };
    const int B = 256;
    const int NB2 = cdiv(M, B);   // 196 <= 256

    // ---- CSR build (count -> scan -> scatter -> bucket sort) ----
    k_cnt<<<SCATB, B, 0, stream>>>(ei, E, ET, chunk, Cmat, nbuck);
    k_scan1<<<NB2, B, 0, stream>>>(Cmat, blkoff, bsum, M);
    k_scan2<<<1, B, 0, stream>>>(bsum, NB2);
    k_scan3<<<NB2, B, 0, stream>>>(blkoff, bsum, off, M, N, ET);
    k_scat<<<SCATB, B, 0, stream>>>(ei, E, ET, chunk, blkoff, pairs, nbuck);
    k_sortB<<<nbuck, B, 0, stream>>>(pairs, blkoff, off, csr_src, N, ET, nbuck);

    // ---- layer 1 (input-space aggregation) ----
    k_attn1<<<cdiv(N, B), B, 0, stream>>>(x, W1, as1, ad1, x8, as4, ad4, N);
    k_agg1x<<<cdiv((long long)N * 16, B), B, 0, stream>>>(off, csr_src, as4, ad4, x8, aggx, N);
    k_expand1<<<cdiv((long long)N * 128, B), B, 0, stream>>>(aggx, W1, b1, out1, N);

    // ---- layer 2 ----
    k_feat2<<<cdiv((long long)N * 32, B), B, 0, stream>>>(out1, W2, as2, ad2, h2, a_s2, a_d2, N);
    k_agg2h<<<cdiv((long long)N * 32, B), B, 0, stream>>>(off, csr_src, a_s2, a_d2, h2, b2,
                                                          Wc1, bc1, Wc2, bc2, out, N);
}

// Round 6
// 169.547 us; speedup vs baseline: 2.0659x; 1.0348x over previous
//
#include <hip/hip_runtime.h>

#define NEG_SLOPE 0.2f
#define BSHIFT 6          // bucket = 64 consecutive dst ids
#define SCATB 64          // blocks in count/scatter phases

__device__ __forceinline__ float elu1(float v) { return v > 0.f ? v : expm1f(v); }
__device__ __forceinline__ float lrelu(float v) { return v > 0.f ? v : NEG_SLOPE * v; }

// ---------------- CSR build: exact-offset bucketing (no global atomics) ----------------

__global__ __launch_bounds__(256) void k_cnt(
    const int* __restrict__ ei, int E, int ET, int chunk,
    int* __restrict__ Cmat, int nbuck) {
    __shared__ int hist[784];
    for (int i = threadIdx.x; i < nbuck; i += 256) hist[i] = 0;
    __syncthreads();
    int k = blockIdx.x;
    int e0 = k * chunk, e1 = min(e0 + chunk, ET);
    for (int e = e0 + threadIdx.x; e < e1; e += 256) {
        int d = (e < E) ? ei[E + e] : e - E;
        atomicAdd(&hist[d >> BSHIFT], 1);
    }
    __syncthreads();
    for (int i = threadIdx.x; i < nbuck; i += 256)
        Cmat[i * SCATB + k] = hist[i];
}

__global__ __launch_bounds__(256) void k_scan1(
    const int* __restrict__ Cmat, int* __restrict__ blkoff, int* __restrict__ bsum, int M) {
    __shared__ int ws4[4], wsoff[4];
    int i = blockIdx.x * 256 + threadIdx.x;
    int lane = threadIdx.x & 63, w = threadIdx.x >> 6;
    int v = (i < M) ? Cmat[i] : 0;
    int sc = v;
#pragma unroll
    for (int m = 1; m < 64; m <<= 1) {
        int t = __shfl_up(sc, m, 64);
        if (lane >= m) sc += t;
    }
    if (lane == 63) ws4[w] = sc;
    __syncthreads();
    if (threadIdx.x == 0) {
        int r = 0;
#pragma unroll
        for (int j = 0; j < 4; ++j) { wsoff[j] = r; r += ws4[j]; }
        bsum[blockIdx.x] = r;
    }
    __syncthreads();
    if (i < M) blkoff[i + 1] = sc + wsoff[w];
}

__global__ __launch_bounds__(256) void k_scan2(int* __restrict__ bsum, int nb) {
    __shared__ int ws4[4], wsoff[4];
    int i = threadIdx.x;
    int lane = i & 63, w = i >> 6;
    int v = (i < nb) ? bsum[i] : 0;
    int sc = v;
#pragma unroll
    for (int m = 1; m < 64; m <<= 1) {
        int t = __shfl_up(sc, m, 64);
        if (lane >= m) sc += t;
    }
    if (lane == 63) ws4[w] = sc;
    __syncthreads();
    if (i == 0) {
        int r = 0;
#pragma unroll
        for (int j = 0; j < 4; ++j) { wsoff[j] = r; r += ws4[j]; }
    }
    __syncthreads();
    if (i < nb) bsum[i] = sc + wsoff[w];
}

__global__ __launch_bounds__(256) void k_scan3(
    int* __restrict__ blkoff, const int* __restrict__ bsum,
    int* __restrict__ off, int M, int N, int ET) {
    int i = blockIdx.x * 256 + threadIdx.x;
    if (i == 0) { blkoff[0] = 0; off[N] = ET; }
    if (i >= M) return;
    if (blockIdx.x > 0) blkoff[i + 1] += bsum[blockIdx.x - 1];
}

__global__ __launch_bounds__(256) void k_scat(
    const int* __restrict__ ei, int E, int ET, int chunk,
    const int* __restrict__ blkoff, unsigned* __restrict__ pairs, int nbuck) {
    __shared__ int cur[784];
    int k = blockIdx.x;
    for (int i = threadIdx.x; i < nbuck; i += 256)
        cur[i] = blkoff[i * SCATB + k];
    __syncthreads();
    int e0 = k * chunk, e1 = min(e0 + chunk, ET);
    for (int e = e0 + threadIdx.x; e < e1; e += 256) {
        int s, d;
        if (e < E) { s = ei[e]; d = ei[E + e]; } else { s = d = e - E; }
        int p = atomicAdd(&cur[d >> BSHIFT], 1);
        pairs[p] = (unsigned)s | ((unsigned)(d & 63) << 16);   // src < 65536
    }
}

__global__ __launch_bounds__(256) void k_sortB(
    const unsigned* __restrict__ pairs, const int* __restrict__ blkoff,
    int* __restrict__ off, int* __restrict__ csr_src, int N, int ET, int nbuck) {
    __shared__ int hist[64], cur[64];
    int b = blockIdx.x;
    int base = blkoff[b * SCATB];
    int end  = (b + 1 < nbuck) ? blkoff[(b + 1) * SCATB] : ET;
    int cnt = end - base;
    int dstBase = b << BSHIFT;
    if (threadIdx.x < 64) hist[threadIdx.x] = 0;
    __syncthreads();
    for (int i = threadIdx.x; i < cnt; i += 256)
        atomicAdd(&hist[pairs[base + i] >> 16], 1);
    __syncthreads();
    if (threadIdx.x < 64) {
        int v = hist[threadIdx.x], sc = v;
#pragma unroll
        for (int m = 1; m < 64; m <<= 1) {
            int t = __shfl_up(sc, m, 64);
            if (threadIdx.x >= m) sc += t;
        }
        int ex = sc - v;
        cur[threadIdx.x] = ex;
        int d = dstBase + threadIdx.x;
        if (d < N) off[d] = base + ex;
    }
    __syncthreads();
    for (int i = threadIdx.x; i < cnt; i += 256) {
        unsigned pr = pairs[base + i];
        int r = atomicAdd(&cur[pr >> 16], 1);
        csr_src[base + r] = (int)(pr & 0xFFFFu);
    }
}

// ---------------- layer 1 (aggregate in 5-dim input space) ----------------

__global__ __launch_bounds__(256) void k_attn1(
    const float* __restrict__ x, const float* __restrict__ W1,
    const float* __restrict__ att_s, const float* __restrict__ att_d,
    float* __restrict__ x8, float4* __restrict__ as4, float4* __restrict__ ad4, int N) {
    __shared__ float Ps[5][4], Pd[5][4];
    if (threadIdx.x < 40) {
        int pair = threadIdx.x & 1, idx = threadIdx.x >> 1;
        int k = idx >> 2, h = idx & 3;
        const float* att = pair ? att_d : att_s;
        float r = 0.f;
#pragma unroll
        for (int c = 0; c < 32; ++c) r = fmaf(W1[k * 128 + h * 32 + c], att[h * 32 + c], r);
        if (pair) Pd[k][h] = r; else Ps[k][h] = r;
    }
    __syncthreads();
    int n = blockIdx.x * 256 + threadIdx.x;
    if (n >= N) return;
    float xv[5];
#pragma unroll
    for (int k = 0; k < 5; ++k) xv[k] = x[(size_t)n * 5 + k];
#pragma unroll
    for (int k = 0; k < 5; ++k) x8[(size_t)n * 8 + k] = xv[k];
    float s0 = 0, s1 = 0, s2 = 0, s3 = 0, d0 = 0, d1 = 0, d2 = 0, d3 = 0;
#pragma unroll
    for (int k = 0; k < 5; ++k) {
        s0 = fmaf(xv[k], Ps[k][0], s0); s1 = fmaf(xv[k], Ps[k][1], s1);
        s2 = fmaf(xv[k], Ps[k][2], s2); s3 = fmaf(xv[k], Ps[k][3], s3);
        d0 = fmaf(xv[k], Pd[k][0], d0); d1 = fmaf(xv[k], Pd[k][1], d1);
        d2 = fmaf(xv[k], Pd[k][2], d2); d3 = fmaf(xv[k], Pd[k][3], d3);
    }
    as4[n] = make_float4(s0, s1, s2, s3);
    ad4[n] = make_float4(d0, d1, d2, d3);
}

// 16-lane group per dst: single-pass softmax-weighted aggregation of x
__global__ __launch_bounds__(256) void k_agg1x(
    const int* __restrict__ off, const int* __restrict__ csr_src,
    const float4* __restrict__ as4, const float4* __restrict__ ad4,
    const float* __restrict__ x8, float* __restrict__ aggx, int N) {
    int g = (blockIdx.x * 256 + threadIdx.x) >> 4;
    int lane = threadIdx.x & 15;
    if (g >= N) return;
    int p0 = off[g], p1 = off[g + 1];
    float4 ad = ad4[g];
    float den0 = 0, den1 = 0, den2 = 0, den3 = 0;
    float acc[4][5] = {};
    for (int p = p0 + lane; p < p1; p += 16) {
        int s = csr_src[p];
        float4 as = as4[s];
        float v0 = __expf(lrelu(as.x + ad.x));
        float v1 = __expf(lrelu(as.y + ad.y));
        float v2 = __expf(lrelu(as.z + ad.z));
        float v3 = __expf(lrelu(as.w + ad.w));
        den0 += v0; den1 += v1; den2 += v2; den3 += v3;
        const float* xr = x8 + (size_t)s * 8;
        float4 xlo = *(const float4*)xr;
        float x4 = xr[4];
        float xk[5] = {xlo.x, xlo.y, xlo.z, xlo.w, x4};
#pragma unroll
        for (int k = 0; k < 5; ++k) {
            acc[0][k] = fmaf(v0, xk[k], acc[0][k]);
            acc[1][k] = fmaf(v1, xk[k], acc[1][k]);
            acc[2][k] = fmaf(v2, xk[k], acc[2][k]);
            acc[3][k] = fmaf(v3, xk[k], acc[3][k]);
        }
    }
#pragma unroll
    for (int m = 8; m; m >>= 1) {
        den0 += __shfl_xor(den0, m, 16); den1 += __shfl_xor(den1, m, 16);
        den2 += __shfl_xor(den2, m, 16); den3 += __shfl_xor(den3, m, 16);
#pragma unroll
        for (int h = 0; h < 4; ++h)
#pragma unroll
            for (int k = 0; k < 5; ++k) acc[h][k] += __shfl_xor(acc[h][k], m, 16);
    }
    if (lane == 0) {
        float i0 = 1.f / den0, i1 = 1.f / den1, i2 = 1.f / den2, i3 = 1.f / den3;
        float4* o = (float4*)(aggx + (size_t)g * 20);
        o[0] = make_float4(acc[0][0] * i0, acc[0][1] * i0, acc[0][2] * i0, acc[0][3] * i0);
        o[1] = make_float4(acc[0][4] * i0, acc[1][0] * i1, acc[1][1] * i1, acc[1][2] * i1);
        o[2] = make_float4(acc[1][3] * i1, acc[1][4] * i1, acc[2][0] * i2, acc[2][1] * i2);
        o[3] = make_float4(acc[2][2] * i2, acc[2][3] * i2, acc[2][4] * i2, acc[3][0] * i3);
        o[4] = make_float4(acc[3][1] * i3, acc[3][2] * i3, acc[3][3] * i3, acc[3][4] * i3);
    }
}

// ---------------- fused expand + layer-2 features ----------------
// h2 = elu(aggx @ W1 + b1) @ W2 per node, 32-lane group, out1 never materialized.
// Also emits a_s2/a_d2 attention dots.
__global__ __launch_bounds__(256) void k_h2f(
    const float* __restrict__ aggx, const float* __restrict__ W1,
    const float* __restrict__ b1, const float* __restrict__ W2,
    const float* __restrict__ att_s, const float* __restrict__ att_d,
    float* __restrict__ h2, float* __restrict__ a_s2, float* __restrict__ a_d2, int N) {
    __shared__ float W1l[5 * 128];
    __shared__ float W2l[128 * 32];
    __shared__ float b1l[128], asl[32], adl[32];
    for (int i = threadIdx.x; i < 5 * 128; i += 256) W1l[i] = W1[i];
    for (int i = threadIdx.x; i < 128 * 32; i += 256) W2l[i] = W2[i];
    if (threadIdx.x < 128) b1l[threadIdx.x] = b1[threadIdx.x];
    if (threadIdx.x < 32) { asl[threadIdx.x] = att_s[threadIdx.x]; adl[threadIdx.x] = att_d[threadIdx.x]; }
    __syncthreads();
    int g = (blockIdx.x * 256 + threadIdx.x) >> 5;
    int c = threadIdx.x & 31;
    if (g >= N) return;
    const float* ag = aggx + (size_t)g * 20;
    float v[4];
#pragma unroll
    for (int h = 0; h < 4; ++h) {
        float r = b1l[h * 32 + c];
#pragma unroll
        for (int j = 0; j < 5; ++j) r = fmaf(ag[h * 5 + j], W1l[j * 128 + h * 32 + c], r);
        v[h] = elu1(r);
    }
    float acc = 0.f;
#pragma unroll 4
    for (int cc = 0; cc < 32; ++cc) {
#pragma unroll
        for (int h = 0; h < 4; ++h) {
            float vh = __shfl(v[h], cc, 32);
            acc = fmaf(vh, W2l[(h * 32 + cc) * 32 + c], acc);
        }
    }
    h2[(size_t)g * 32 + c] = acc;
    float as = acc * asl[c], ad = acc * adl[c];
#pragma unroll
    for (int m = 16; m; m >>= 1) {
        as += __shfl_xor(as, m, 32);
        ad += __shfl_xor(ad, m, 32);
    }
    if (c == 0) { a_s2[g] = as; a_d2[g] = ad; }
}

// ---------------- layer-2 aggregation + fused MLP head ----------------
// 32-lane group per dst. Coalesced edge-index loads; ONE exp per edge (lane-owned),
// then shuffle-broadcast accumulation of coalesced 128B h2 rows (padded, unroll-4).
__global__ __launch_bounds__(256) void k_agg2h(
    const int* __restrict__ off, const int* __restrict__ csr_src,
    const float* __restrict__ a_s, const float* __restrict__ a_d,
    const float* __restrict__ h2, const float* __restrict__ b2,
    const float* __restrict__ Wc1, const float* __restrict__ bc1,
    const float* __restrict__ Wc2, const float* __restrict__ bc2,
    float* __restrict__ out, int N) {
    __shared__ float Wl[512];
    __shared__ float b2l[32], b1l[16], w2l[16];
    for (int i = threadIdx.x; i < 512; i += 256) Wl[i] = Wc1[i];
    if (threadIdx.x < 32) b2l[threadIdx.x] = b2[threadIdx.x];
    if (threadIdx.x < 16) {
        b1l[threadIdx.x] = bc1[threadIdx.x];
        w2l[threadIdx.x] = Wc2[threadIdx.x];
    }
    __syncthreads();
    int g = (blockIdx.x * 256 + threadIdx.x) >> 5;
    int lane = threadIdx.x & 31;
    if (g >= N) return;
    int p0 = off[g], p1 = off[g + 1];
    float ad = a_d[g];
    float acc = 0.f, den = 0.f;
    for (int base = p0; base < p1; base += 32) {
        int rem = p1 - base;
        int s = g;                 // safe index for padded lanes
        float w = 0.f;
        if (lane < rem) {
            s = csr_src[base + lane];           // coalesced
            w = __expf(lrelu(a_s[s] + ad));     // one exp per edge
        }
        den += w;
        int cnt = min(rem, 32);
        int rc = (cnt + 3) & ~3;   // pad to multiple of 4 (w=0 beyond cnt)
        for (int j = 0; j < rc; j += 4) {
#pragma unroll
            for (int jj = 0; jj < 4; ++jj) {
                int   sj = __shfl(s, j + jj, 32);
                float wj = __shfl(w, j + jj, 32);
                acc = fmaf(wj, h2[(size_t)sj * 32 + lane], acc);
            }
        }
    }
#pragma unroll
    for (int m = 16; m; m >>= 1) den += __shfl_xor(den, m, 32);
    float z = elu1(fmaf(acc, 1.f / den, b2l[lane]));
    float y = b1l[lane & 15];
#pragma unroll
    for (int c = 0; c < 32; ++c) {
        float zc = __shfl(z, c, 32);
        y = fmaf(zc, Wl[c * 16 + (lane & 15)], y);
    }
    y = fmaxf(y, 0.f);
    float t = (lane < 16) ? y * w2l[lane] : 0.f;
#pragma unroll
    for (int m = 8; m; m >>= 1) t += __shfl_xor(t, m, 32);
    if (lane == 0) out[g] = t + bc2[0];
}

extern "C" void kernel_launch(void* const* d_in, const int* in_sizes, int n_in,
                              void* d_out, int out_size, void* d_ws, size_t ws_size,
                              hipStream_t stream) {
    const float* x   = (const float*)d_in[0];
    const int*   ei  = (const int*)d_in[1];
    const float* W1  = (const float*)d_in[2];
    const float* as1 = (const float*)d_in[3];
    const float* ad1 = (const float*)d_in[4];
    const float* b1  = (const float*)d_in[5];
    const float* W2  = (const float*)d_in[6];
    const float* as2 = (const float*)d_in[7];
    const float* ad2 = (const float*)d_in[8];
    const float* b2  = (const float*)d_in[9];
    const float* Wc1 = (const float*)d_in[10];
    const float* bc1 = (const float*)d_in[11];
    const float* Wc2 = (const float*)d_in[12];
    const float* bc2 = (const float*)d_in[13];
    float* out = (float*)d_out;

    const int N = out_size;                  // 50000
    const int E = in_sizes[1] / 2;           // 800000
    const int ET = E + N;                    // + self loops
    const int nbuck = (N + 63) >> BSHIFT;    // 782
    const int M = nbuck * SCATB;             // 50048 scan elements
    const int chunk = (ET + SCATB - 1) / SCATB;

    // Workspace layout
    float*    ws    = (float*)d_ws;
    float*    h2    = ws;                               // N*32
    float*    x8    = h2   + (size_t)N * 32;            // N*8
    float4*   as4   = (float4*)(x8 + (size_t)N * 8);    // N float4
    float4*   ad4   = as4 + N;                          // N float4
    float*    aggx  = (float*)(ad4 + N);                // N*20
    float*    a_s2  = aggx + (size_t)N * 20;            // N
    float*    a_d2  = a_s2 + N;                         // N
    int*      off   = (int*)(a_d2 + N);                 // N+1
    int*      csr_src = off + (N + 2);                  // ET
    int*      Cmat  = csr_src + ET;                     // M
    int*      blkoff = Cmat + M;                        // M+1
    int*      bsum  = blkoff + (M + 2);                 // 256
    unsigned* pairs = (unsigned*)(bsum + 256);          // ET

    auto cdiv = [](long long a, long long b) { return (int)((a + b - 1) / b); };
    const int B = 256;
    const int NB2 = cdiv(M, B);   // 196 <= 256

    // ---- CSR build (count -> scan -> scatter -> bucket sort) ----
    k_cnt<<<SCATB, B, 0, stream>>>(ei, E, ET, chunk, Cmat, nbuck);
    k_scan1<<<NB2, B, 0, stream>>>(Cmat, blkoff, bsum, M);
    k_scan2<<<1, B, 0, stream>>>(bsum, NB2);
    k_scan3<<<NB2, B, 0, stream>>>(blkoff, bsum, off, M, N, ET);
    k_scat<<<SCATB, B, 0, stream>>>(ei, E, ET, chunk, blkoff, pairs, nbuck);
    k_sortB<<<nbuck, B, 0, stream>>>(pairs, blkoff, off, csr_src, N, ET, nbuck);

    // ---- layer 1 (input-space aggregation) ----
    k_attn1<<<cdiv(N, B), B, 0, stream>>>(x, W1, as1, ad1, x8, as4, ad4, N);
    k_agg1x<<<cdiv((long long)N * 16, B), B, 0, stream>>>(off, csr_src, as4, ad4, x8, aggx, N);

    // ---- fused expand + layer-2 features ----
    k_h2f<<<cdiv((long long)N * 32, B), B, 0, stream>>>(aggx, W1, b1, W2, as2, ad2,
                                                        h2, a_s2, a_d2, N);

    // ---- layer-2 aggregation + head ----
    k_agg2h<<<cdiv((long long)N * 32, B), B, 0, stream>>>(off, csr_src, a_s2, a_d2, h2, b2,
                                                          Wc1, bc1, Wc2, bc2, out, N);
}

// Round 7
// 166.595 us; speedup vs baseline: 2.1025x; 1.0177x over previous
//
#include <hip/hip_runtime.h>

#define NEG_SLOPE 0.2f
#define BSHIFT 6          // bucket = 64 consecutive dst ids
#define SCATB 64          // blocks in count/scatter phases

__device__ __forceinline__ float elu1(float v) { return v > 0.f ? v : expm1f(v); }
__device__ __forceinline__ float lrelu(float v) { return v > 0.f ? v : NEG_SLOPE * v; }

// ---------------- CSR build: exact-offset bucketing (no global atomics) ----------------

__global__ __launch_bounds__(256) void k_cnt(
    const int* __restrict__ ei, int E, int ET, int chunk,
    int* __restrict__ Cmat, int nbuck) {
    __shared__ int hist[784];
    for (int i = threadIdx.x; i < nbuck; i += 256) hist[i] = 0;
    __syncthreads();
    int k = blockIdx.x;
    int e0 = k * chunk, e1 = min(e0 + chunk, ET);
    for (int e = e0 + threadIdx.x; e < e1; e += 256) {
        int d = (e < E) ? ei[E + e] : e - E;
        atomicAdd(&hist[d >> BSHIFT], 1);
    }
    __syncthreads();
    for (int i = threadIdx.x; i < nbuck; i += 256)
        Cmat[i * SCATB + k] = hist[i];
}

__global__ __launch_bounds__(256) void k_scan1(
    const int* __restrict__ Cmat, int* __restrict__ blkoff, int* __restrict__ bsum, int M) {
    __shared__ int ws4[4], wsoff[4];
    int i = blockIdx.x * 256 + threadIdx.x;
    int lane = threadIdx.x & 63, w = threadIdx.x >> 6;
    int v = (i < M) ? Cmat[i] : 0;
    int sc = v;
#pragma unroll
    for (int m = 1; m < 64; m <<= 1) {
        int t = __shfl_up(sc, m, 64);
        if (lane >= m) sc += t;
    }
    if (lane == 63) ws4[w] = sc;
    __syncthreads();
    if (threadIdx.x == 0) {
        int r = 0;
#pragma unroll
        for (int j = 0; j < 4; ++j) { wsoff[j] = r; r += ws4[j]; }
        bsum[blockIdx.x] = r;
    }
    __syncthreads();
    if (i < M) blkoff[i + 1] = sc + wsoff[w];
}

__global__ __launch_bounds__(256) void k_scan2(int* __restrict__ bsum, int nb) {
    __shared__ int ws4[4], wsoff[4];
    int i = threadIdx.x;
    int lane = i & 63, w = i >> 6;
    int v = (i < nb) ? bsum[i] : 0;
    int sc = v;
#pragma unroll
    for (int m = 1; m < 64; m <<= 1) {
        int t = __shfl_up(sc, m, 64);
        if (lane >= m) sc += t;
    }
    if (lane == 63) ws4[w] = sc;
    __syncthreads();
    if (i == 0) {
        int r = 0;
#pragma unroll
        for (int j = 0; j < 4; ++j) { wsoff[j] = r; r += ws4[j]; }
    }
    __syncthreads();
    if (i < nb) bsum[i] = sc + wsoff[w];
}

__global__ __launch_bounds__(256) void k_scan3(
    int* __restrict__ blkoff, const int* __restrict__ bsum,
    int* __restrict__ off, int M, int N, int ET) {
    int i = blockIdx.x * 256 + threadIdx.x;
    if (i == 0) { blkoff[0] = 0; off[N] = ET; }
    if (i >= M) return;
    if (blockIdx.x > 0) blkoff[i + 1] += bsum[blockIdx.x - 1];
}

__global__ __launch_bounds__(256) void k_scat(
    const int* __restrict__ ei, int E, int ET, int chunk,
    const int* __restrict__ blkoff, unsigned* __restrict__ pairs, int nbuck) {
    __shared__ int cur[784];
    int k = blockIdx.x;
    for (int i = threadIdx.x; i < nbuck; i += 256)
        cur[i] = blkoff[i * SCATB + k];
    __syncthreads();
    int e0 = k * chunk, e1 = min(e0 + chunk, ET);
    for (int e = e0 + threadIdx.x; e < e1; e += 256) {
        int s, d;
        if (e < E) { s = ei[e]; d = ei[E + e]; } else { s = d = e - E; }
        int p = atomicAdd(&cur[d >> BSHIFT], 1);
        pairs[p] = (unsigned)s | ((unsigned)(d & 63) << 16);   // src < 65536
    }
}

__global__ __launch_bounds__(256) void k_sortB(
    const unsigned* __restrict__ pairs, const int* __restrict__ blkoff,
    int* __restrict__ off, int* __restrict__ csr_src, int N, int ET, int nbuck) {
    __shared__ int hist[64], cur[64];
    int b = blockIdx.x;
    int base = blkoff[b * SCATB];
    int end  = (b + 1 < nbuck) ? blkoff[(b + 1) * SCATB] : ET;
    int cnt = end - base;
    int dstBase = b << BSHIFT;
    if (threadIdx.x < 64) hist[threadIdx.x] = 0;
    __syncthreads();
    for (int i = threadIdx.x; i < cnt; i += 256)
        atomicAdd(&hist[pairs[base + i] >> 16], 1);
    __syncthreads();
    if (threadIdx.x < 64) {
        int v = hist[threadIdx.x], sc = v;
#pragma unroll
        for (int m = 1; m < 64; m <<= 1) {
            int t = __shfl_up(sc, m, 64);
            if (threadIdx.x >= m) sc += t;
        }
        int ex = sc - v;
        cur[threadIdx.x] = ex;
        int d = dstBase + threadIdx.x;
        if (d < N) off[d] = base + ex;
    }
    __syncthreads();
    for (int i = threadIdx.x; i < cnt; i += 256) {
        unsigned pr = pairs[base + i];
        int r = atomicAdd(&cur[pr >> 16], 1);
        csr_src[base + r] = (int)(pr & 0xFFFFu);
    }
}

// ---------------- layer 1 (aggregate in 5-dim input space) ----------------

__global__ __launch_bounds__(256) void k_attn1(
    const float* __restrict__ x, const float* __restrict__ W1,
    const float* __restrict__ att_s, const float* __restrict__ att_d,
    float* __restrict__ x8, float4* __restrict__ as4, float4* __restrict__ ad4, int N) {
    __shared__ float Ps[5][4], Pd[5][4];
    if (threadIdx.x < 40) {
        int pair = threadIdx.x & 1, idx = threadIdx.x >> 1;
        int k = idx >> 2, h = idx & 3;
        const float* att = pair ? att_d : att_s;
        float r = 0.f;
#pragma unroll
        for (int c = 0; c < 32; ++c) r = fmaf(W1[k * 128 + h * 32 + c], att[h * 32 + c], r);
        if (pair) Pd[k][h] = r; else Ps[k][h] = r;
    }
    __syncthreads();
    int n = blockIdx.x * 256 + threadIdx.x;
    if (n >= N) return;
    float xv[5];
#pragma unroll
    for (int k = 0; k < 5; ++k) xv[k] = x[(size_t)n * 5 + k];
#pragma unroll
    for (int k = 0; k < 5; ++k) x8[(size_t)n * 8 + k] = xv[k];
    float s0 = 0, s1 = 0, s2 = 0, s3 = 0, d0 = 0, d1 = 0, d2 = 0, d3 = 0;
#pragma unroll
    for (int k = 0; k < 5; ++k) {
        s0 = fmaf(xv[k], Ps[k][0], s0); s1 = fmaf(xv[k], Ps[k][1], s1);
        s2 = fmaf(xv[k], Ps[k][2], s2); s3 = fmaf(xv[k], Ps[k][3], s3);
        d0 = fmaf(xv[k], Pd[k][0], d0); d1 = fmaf(xv[k], Pd[k][1], d1);
        d2 = fmaf(xv[k], Pd[k][2], d2); d3 = fmaf(xv[k], Pd[k][3], d3);
    }
    as4[n] = make_float4(s0, s1, s2, s3);
    ad4[n] = make_float4(d0, d1, d2, d3);
}

// 16-lane group per dst: single-pass softmax-weighted aggregation of x
__global__ __launch_bounds__(256) void k_agg1x(
    const int* __restrict__ off, const int* __restrict__ csr_src,
    const float4* __restrict__ as4, const float4* __restrict__ ad4,
    const float* __restrict__ x8, float* __restrict__ aggx, int N) {
    int g = (blockIdx.x * 256 + threadIdx.x) >> 4;
    int lane = threadIdx.x & 15;
    if (g >= N) return;
    int p0 = off[g], p1 = off[g + 1];
    float4 ad = ad4[g];
    float den0 = 0, den1 = 0, den2 = 0, den3 = 0;
    float acc[4][5] = {};
    for (int p = p0 + lane; p < p1; p += 16) {
        int s = csr_src[p];
        float4 as = as4[s];
        float v0 = __expf(lrelu(as.x + ad.x));
        float v1 = __expf(lrelu(as.y + ad.y));
        float v2 = __expf(lrelu(as.z + ad.z));
        float v3 = __expf(lrelu(as.w + ad.w));
        den0 += v0; den1 += v1; den2 += v2; den3 += v3;
        const float* xr = x8 + (size_t)s * 8;
        float4 xlo = *(const float4*)xr;
        float x4 = xr[4];
        float xk[5] = {xlo.x, xlo.y, xlo.z, xlo.w, x4};
#pragma unroll
        for (int k = 0; k < 5; ++k) {
            acc[0][k] = fmaf(v0, xk[k], acc[0][k]);
            acc[1][k] = fmaf(v1, xk[k], acc[1][k]);
            acc[2][k] = fmaf(v2, xk[k], acc[2][k]);
            acc[3][k] = fmaf(v3, xk[k], acc[3][k]);
        }
    }
#pragma unroll
    for (int m = 8; m; m >>= 1) {
        den0 += __shfl_xor(den0, m, 16); den1 += __shfl_xor(den1, m, 16);
        den2 += __shfl_xor(den2, m, 16); den3 += __shfl_xor(den3, m, 16);
#pragma unroll
        for (int h = 0; h < 4; ++h)
#pragma unroll
            for (int k = 0; k < 5; ++k) acc[h][k] += __shfl_xor(acc[h][k], m, 16);
    }
    if (lane == 0) {
        float i0 = 1.f / den0, i1 = 1.f / den1, i2 = 1.f / den2, i3 = 1.f / den3;
        float4* o = (float4*)(aggx + (size_t)g * 20);
        o[0] = make_float4(acc[0][0] * i0, acc[0][1] * i0, acc[0][2] * i0, acc[0][3] * i0);
        o[1] = make_float4(acc[0][4] * i0, acc[1][0] * i1, acc[1][1] * i1, acc[1][2] * i1);
        o[2] = make_float4(acc[1][3] * i1, acc[1][4] * i1, acc[2][0] * i2, acc[2][1] * i2);
        o[3] = make_float4(acc[2][2] * i2, acc[2][3] * i2, acc[2][4] * i2, acc[3][0] * i3);
        o[4] = make_float4(acc[3][1] * i3, acc[3][2] * i3, acc[3][3] * i3, acc[3][4] * i3);
    }
}

// out1 = elu(aggx @ W1 + b1)   [N,4,5] x [5,128] -> [N,128]
__global__ __launch_bounds__(256) void k_expand1(
    const float* __restrict__ aggx, const float* __restrict__ W1,
    const float* __restrict__ b1, float* __restrict__ out1, int N) {
    __shared__ float Wl[5 * 128];
    for (int i = threadIdx.x; i < 5 * 128; i += 256) Wl[i] = W1[i];
    __syncthreads();
    int t = blockIdx.x * 256 + threadIdx.x;
    int n = t >> 7, c = t & 127;
    if (n >= N) return;
    int h = c >> 5;
    const float* ag = aggx + (size_t)n * 20 + h * 5;
    float r = b1[c];
#pragma unroll
    for (int k = 0; k < 5; ++k) r = fmaf(ag[k], Wl[k * 128 + c], r);
    out1[(size_t)n * 128 + c] = elu1(r);
}

// h2 = out1 @ W2 (128 -> 32) + single-head attention dots
__global__ __launch_bounds__(256) void k_feat2(
    const float* __restrict__ h1b, const float* __restrict__ W2,
    const float* __restrict__ att_s, const float* __restrict__ att_d,
    float* __restrict__ h2, float* __restrict__ a_s, float* __restrict__ a_d, int N) {
    __shared__ float Wl[128 * 32];
    for (int i = threadIdx.x; i < 128 * 32; i += 256) Wl[i] = W2[i];
    __syncthreads();
    int t = blockIdx.x * 256 + threadIdx.x;
    int n = t >> 5, c = t & 31;
    if (n >= N) return;
    const float4* hr4 = (const float4*)(h1b + (size_t)n * 128);
    float acc = 0.f;
#pragma unroll
    for (int k4 = 0; k4 < 32; ++k4) {
        float4 hv = hr4[k4];
        acc = fmaf(hv.x, Wl[(k4 * 4 + 0) * 32 + c], acc);
        acc = fmaf(hv.y, Wl[(k4 * 4 + 1) * 32 + c], acc);
        acc = fmaf(hv.z, Wl[(k4 * 4 + 2) * 32 + c], acc);
        acc = fmaf(hv.w, Wl[(k4 * 4 + 3) * 32 + c], acc);
    }
    h2[(size_t)n * 32 + c] = acc;
    float as = acc * att_s[c], ad = acc * att_d[c];
#pragma unroll
    for (int m = 16; m; m >>= 1) {
        as += __shfl_xor(as, m, 32);
        ad += __shfl_xor(ad, m, 32);
    }
    if (c == 0) { a_s[n] = as; a_d[n] = ad; }
}

// ---------------- layer-2 aggregation + fused MLP head ----------------
// 32-lane group per dst. Coalesced edge-index loads; ONE exp per edge (lane-owned),
// then shuffle-broadcast accumulation of coalesced 128B h2 rows (padded, unroll-4).
__global__ __launch_bounds__(256) void k_agg2h(
    const int* __restrict__ off, const int* __restrict__ csr_src,
    const float* __restrict__ a_s, const float* __restrict__ a_d,
    const float* __restrict__ h2, const float* __restrict__ b2,
    const float* __restrict__ Wc1, const float* __restrict__ bc1,
    const float* __restrict__ Wc2, const float* __restrict__ bc2,
    float* __restrict__ out, int N) {
    __shared__ float Wl[512];
    __shared__ float b2l[32], b1l[16], w2l[16];
    for (int i = threadIdx.x; i < 512; i += 256) Wl[i] = Wc1[i];
    if (threadIdx.x < 32) b2l[threadIdx.x] = b2[threadIdx.x];
    if (threadIdx.x < 16) {
        b1l[threadIdx.x] = bc1[threadIdx.x];
        w2l[threadIdx.x] = Wc2[threadIdx.x];
    }
    __syncthreads();
    int g = (blockIdx.x * 256 + threadIdx.x) >> 5;
    int lane = threadIdx.x & 31;
    if (g >= N) return;
    int p0 = off[g], p1 = off[g + 1];
    float ad = a_d[g];
    float acc = 0.f, den = 0.f;
    for (int base = p0; base < p1; base += 32) {
        int rem = p1 - base;
        int s = g;                 // safe index for padded lanes
        float w = 0.f;
        if (lane < rem) {
            s = csr_src[base + lane];           // coalesced
            w = __expf(lrelu(a_s[s] + ad));     // one exp per edge
        }
        den += w;
        int cnt = min(rem, 32);
        int rc = (cnt + 3) & ~3;   // pad to multiple of 4 (w=0 beyond cnt)
        for (int j = 0; j < rc; j += 4) {
#pragma unroll
            for (int jj = 0; jj < 4; ++jj) {
                int   sj = __shfl(s, j + jj, 32);
                float wj = __shfl(w, j + jj, 32);
                acc = fmaf(wj, h2[(size_t)sj * 32 + lane], acc);
            }
        }
    }
#pragma unroll
    for (int m = 16; m; m >>= 1) den += __shfl_xor(den, m, 32);
    float z = elu1(fmaf(acc, 1.f / den, b2l[lane]));
    float y = b1l[lane & 15];
#pragma unroll
    for (int c = 0; c < 32; ++c) {
        float zc = __shfl(z, c, 32);
        y = fmaf(zc, Wl[c * 16 + (lane & 15)], y);
    }
    y = fmaxf(y, 0.f);
    float t = (lane < 16) ? y * w2l[lane] : 0.f;
#pragma unroll
    for (int m = 8; m; m >>= 1) t += __shfl_xor(t, m, 32);
    if (lane == 0) out[g] = t + bc2[0];
}

extern "C" void kernel_launch(void* const* d_in, const int* in_sizes, int n_in,
                              void* d_out, int out_size, void* d_ws, size_t ws_size,
                              hipStream_t stream) {
    const float* x   = (const float*)d_in[0];
    const int*   ei  = (const int*)d_in[1];
    const float* W1  = (const float*)d_in[2];
    const float* as1 = (const float*)d_in[3];
    const float* ad1 = (const float*)d_in[4];
    const float* b1  = (const float*)d_in[5];
    const float* W2  = (const float*)d_in[6];
    const float* as2 = (const float*)d_in[7];
    const float* ad2 = (const float*)d_in[8];
    const float* b2  = (const float*)d_in[9];
    const float* Wc1 = (const float*)d_in[10];
    const float* bc1 = (const float*)d_in[11];
    const float* Wc2 = (const float*)d_in[12];
    const float* bc2 = (const float*)d_in[13];
    float* out = (float*)d_out;

    const int N = out_size;                  // 50000
    const int E = in_sizes[1] / 2;           // 800000
    const int ET = E + N;                    // + self loops
    const int nbuck = (N + 63) >> BSHIFT;    // 782
    const int M = nbuck * SCATB;             // 50048 scan elements
    const int chunk = (ET + SCATB - 1) / SCATB;

    // Workspace layout
    float*    ws    = (float*)d_ws;
    float*    out1  = ws;                               // N*128
    float*    h2    = out1 + (size_t)N * 128;           // N*32
    float*    x8    = h2   + (size_t)N * 32;            // N*8
    float4*   as4   = (float4*)(x8 + (size_t)N * 8);    // N float4
    float4*   ad4   = as4 + N;                          // N float4
    float*    aggx  = (float*)(ad4 + N);                // N*20
    float*    a_s2  = aggx + (size_t)N * 20;            // N
    float*    a_d2  = a_s2 + N;                         // N
    int*      off   = (int*)(a_d2 + N);                 // N+1
    int*      csr_src = off + (N + 2);                  // ET
    int*      Cmat  = csr_src + ET;                     // M
    int*      blkoff = Cmat + M;                        // M+1
    int*      bsum  = blkoff + (M + 2);                 // 256
    unsigned* pairs = (unsigned*)(bsum + 256);          // ET

    auto cdiv = [](long long a, long long b) { return (int)((a + b - 1) / b); };
    const int B = 256;
    const int NB2 = cdiv(M, B);   // 196 <= 256

    // ---- CSR build (count -> scan -> scatter -> bucket sort) ----
    k_cnt<<<SCATB, B, 0, stream>>>(ei, E, ET, chunk, Cmat, nbuck);
    k_scan1<<<NB2, B, 0, stream>>>(Cmat, blkoff, bsum, M);
    k_scan2<<<1, B, 0, stream>>>(bsum, NB2);
    k_scan3<<<NB2, B, 0, stream>>>(blkoff, bsum, off, M, N, ET);
    k_scat<<<SCATB, B, 0, stream>>>(ei, E, ET, chunk, blkoff, pairs, nbuck);
    k_sortB<<<nbuck, B, 0, stream>>>(pairs, blkoff, off, csr_src, N, ET, nbuck);

    // ---- layer 1 (input-space aggregation) ----
    k_attn1<<<cdiv(N, B), B, 0, stream>>>(x, W1, as1, ad1, x8, as4, ad4, N);
    k_agg1x<<<cdiv((long long)N * 16, B), B, 0, stream>>>(off, csr_src, as4, ad4, x8, aggx, N);
    k_expand1<<<cdiv((long long)N * 128, B), B, 0, stream>>>(aggx, W1, b1, out1, N);

    // ---- layer 2 ----
    k_feat2<<<cdiv((long long)N * 32, B), B, 0, stream>>>(out1, W2, as2, ad2, h2, a_s2, a_d2, N);
    k_agg2h<<<cdiv((long long)N * 32, B), B, 0, stream>>>(off, csr_src, a_s2, a_d2, h2, b2,
                                                          Wc1, bc1, Wc2, bc2, out, N);
}

// Round 8
// 156.199 us; speedup vs baseline: 2.2424x; 1.0666x over previous
//
#include <hip/hip_runtime.h>

#define NEG_SLOPE 0.2f
#define BSHIFT 6          // bucket = 64 consecutive dst ids
#define SCATB 64          // blocks in count/scatter phases

__device__ __forceinline__ float elu1(float v) { return v > 0.f ? v : expm1f(v); }
__device__ __forceinline__ float lrelu(float v) { return v > 0.f ? v : NEG_SLOPE * v; }

// ---------------- CSR build: exact-offset bucketing (no global atomics) ----------------

__global__ __launch_bounds__(256) void k_cnt(
    const int* __restrict__ ei, int E, int ET, int chunk,
    int* __restrict__ Cmat, int nbuck) {
    __shared__ int hist[784];
    for (int i = threadIdx.x; i < nbuck; i += 256) hist[i] = 0;
    __syncthreads();
    int k = blockIdx.x;
    int e0 = k * chunk, e1 = min(e0 + chunk, ET);
    for (int e = e0 + threadIdx.x; e < e1; e += 256) {
        int d = (e < E) ? ei[E + e] : e - E;
        atomicAdd(&hist[d >> BSHIFT], 1);
    }
    __syncthreads();
    for (int i = threadIdx.x; i < nbuck; i += 256)
        Cmat[i * SCATB + k] = hist[i];
}

__global__ __launch_bounds__(256) void k_scan1(
    const int* __restrict__ Cmat, int* __restrict__ blkoff, int* __restrict__ bsum, int M) {
    __shared__ int ws4[4], wsoff[4];
    int i = blockIdx.x * 256 + threadIdx.x;
    int lane = threadIdx.x & 63, w = threadIdx.x >> 6;
    int v = (i < M) ? Cmat[i] : 0;
    int sc = v;
#pragma unroll
    for (int m = 1; m < 64; m <<= 1) {
        int t = __shfl_up(sc, m, 64);
        if (lane >= m) sc += t;
    }
    if (lane == 63) ws4[w] = sc;
    __syncthreads();
    if (threadIdx.x == 0) {
        int r = 0;
#pragma unroll
        for (int j = 0; j < 4; ++j) { wsoff[j] = r; r += ws4[j]; }
        bsum[blockIdx.x] = r;
    }
    __syncthreads();
    if (i < M) blkoff[i + 1] = sc + wsoff[w];
}

__global__ __launch_bounds__(256) void k_scan2(int* __restrict__ bsum, int nb) {
    __shared__ int ws4[4], wsoff[4];
    int i = threadIdx.x;
    int lane = i & 63, w = i >> 6;
    int v = (i < nb) ? bsum[i] : 0;
    int sc = v;
#pragma unroll
    for (int m = 1; m < 64; m <<= 1) {
        int t = __shfl_up(sc, m, 64);
        if (lane >= m) sc += t;
    }
    if (lane == 63) ws4[w] = sc;
    __syncthreads();
    if (i == 0) {
        int r = 0;
#pragma unroll
        for (int j = 0; j < 4; ++j) { wsoff[j] = r; r += ws4[j]; }
    }
    __syncthreads();
    if (i < nb) bsum[i] = sc + wsoff[w];
}

__global__ __launch_bounds__(256) void k_scan3(
    int* __restrict__ blkoff, const int* __restrict__ bsum,
    int* __restrict__ off, int M, int N, int ET) {
    int i = blockIdx.x * 256 + threadIdx.x;
    if (i == 0) { blkoff[0] = 0; off[N] = ET; }
    if (i >= M) return;
    if (blockIdx.x > 0) blkoff[i + 1] += bsum[blockIdx.x - 1];
}

__global__ __launch_bounds__(256) void k_scat(
    const int* __restrict__ ei, int E, int ET, int chunk,
    const int* __restrict__ blkoff, unsigned* __restrict__ pairs, int nbuck) {
    __shared__ int cur[784];
    int k = blockIdx.x;
    for (int i = threadIdx.x; i < nbuck; i += 256)
        cur[i] = blkoff[i * SCATB + k];
    __syncthreads();
    int e0 = k * chunk, e1 = min(e0 + chunk, ET);
    for (int e = e0 + threadIdx.x; e < e1; e += 256) {
        int s, d;
        if (e < E) { s = ei[e]; d = ei[E + e]; } else { s = d = e - E; }
        int p = atomicAdd(&cur[d >> BSHIFT], 1);
        pairs[p] = (unsigned)s | ((unsigned)(d & 63) << 16);   // src < 65536
    }
}

__global__ __launch_bounds__(256) void k_sortB(
    const unsigned* __restrict__ pairs, const int* __restrict__ blkoff,
    int* __restrict__ off, int* __restrict__ csr_src, int N, int ET, int nbuck) {
    __shared__ int hist[64], cur[64];
    int b = blockIdx.x;
    int base = blkoff[b * SCATB];
    int end  = (b + 1 < nbuck) ? blkoff[(b + 1) * SCATB] : ET;
    int cnt = end - base;
    int dstBase = b << BSHIFT;
    if (threadIdx.x < 64) hist[threadIdx.x] = 0;
    __syncthreads();
    for (int i = threadIdx.x; i < cnt; i += 256)
        atomicAdd(&hist[pairs[base + i] >> 16], 1);
    __syncthreads();
    if (threadIdx.x < 64) {
        int v = hist[threadIdx.x], sc = v;
#pragma unroll
        for (int m = 1; m < 64; m <<= 1) {
            int t = __shfl_up(sc, m, 64);
            if (threadIdx.x >= m) sc += t;
        }
        int ex = sc - v;
        cur[threadIdx.x] = ex;
        int d = dstBase + threadIdx.x;
        if (d < N) off[d] = base + ex;
    }
    __syncthreads();
    for (int i = threadIdx.x; i < cnt; i += 256) {
        unsigned pr = pairs[base + i];
        int r = atomicAdd(&cur[pr >> 16], 1);
        csr_src[base + r] = (int)(pr & 0xFFFFu);
    }
}

// ---------------- layer 1 ----------------

// per node: packed 64B record rec[16] = {as4[0:4), x[4:9), pad, ad4[12:16)}
__global__ __launch_bounds__(256) void k_attn1(
    const float* __restrict__ x, const float* __restrict__ W1,
    const float* __restrict__ att_s, const float* __restrict__ att_d,
    float* __restrict__ rec, int N) {
    __shared__ float Ps[5][4], Pd[5][4];
    if (threadIdx.x < 40) {
        int pair = threadIdx.x & 1, idx = threadIdx.x >> 1;
        int k = idx >> 2, h = idx & 3;
        const float* att = pair ? att_d : att_s;
        float r = 0.f;
#pragma unroll
        for (int c = 0; c < 32; ++c) r = fmaf(W1[k * 128 + h * 32 + c], att[h * 32 + c], r);
        if (pair) Pd[k][h] = r; else Ps[k][h] = r;
    }
    __syncthreads();
    int n = blockIdx.x * 256 + threadIdx.x;
    if (n >= N) return;
    float xv[5];
#pragma unroll
    for (int k = 0; k < 5; ++k) xv[k] = x[(size_t)n * 5 + k];
    float s0 = 0, s1 = 0, s2 = 0, s3 = 0, d0 = 0, d1 = 0, d2 = 0, d3 = 0;
#pragma unroll
    for (int k = 0; k < 5; ++k) {
        s0 = fmaf(xv[k], Ps[k][0], s0); s1 = fmaf(xv[k], Ps[k][1], s1);
        s2 = fmaf(xv[k], Ps[k][2], s2); s3 = fmaf(xv[k], Ps[k][3], s3);
        d0 = fmaf(xv[k], Pd[k][0], d0); d1 = fmaf(xv[k], Pd[k][1], d1);
        d2 = fmaf(xv[k], Pd[k][2], d2); d3 = fmaf(xv[k], Pd[k][3], d3);
    }
    float* r = rec + (size_t)n * 16;
    *(float4*)(r)     = make_float4(s0, s1, s2, s3);
    *(float4*)(r + 4) = make_float4(xv[0], xv[1], xv[2], xv[3]);
    r[8] = xv[4];
    *(float4*)(r + 12) = make_float4(d0, d1, d2, d3);
}

// 16-lane group per dst: softmax-weighted aggregation of x (one 64B line per edge)
// + fused expand: after the butterfly reduce every lane holds all 20 agg values,
// so each lane directly computes 8 output channels of out1 = elu(agg@W1 + b1).
__global__ __launch_bounds__(256) void k_agg1(
    const int* __restrict__ off, const int* __restrict__ csr_src,
    const float* __restrict__ rec, const float* __restrict__ W1,
    const float* __restrict__ b1, float* __restrict__ out1, int N) {
    __shared__ float Wl[5 * 128];
    __shared__ float b1l[128];
    for (int i = threadIdx.x; i < 5 * 128; i += 256) Wl[i] = W1[i];
    if (threadIdx.x < 128) b1l[threadIdx.x] = b1[threadIdx.x];
    __syncthreads();
    int g = (blockIdx.x * 256 + threadIdx.x) >> 4;
    int lane = threadIdx.x & 15;
    if (g >= N) return;
    int p0 = off[g], p1 = off[g + 1];
    float4 ad = *(const float4*)(rec + (size_t)g * 16 + 12);
    float den0 = 0, den1 = 0, den2 = 0, den3 = 0;
    float acc[4][5] = {};
    for (int p = p0 + lane; p < p1; p += 16) {
        int s = csr_src[p];
        const float* r = rec + (size_t)s * 16;
        float4 as  = *(const float4*)r;
        float4 x03 = *(const float4*)(r + 4);
        float  x4  = r[8];
        float v0 = __expf(lrelu(as.x + ad.x));
        float v1 = __expf(lrelu(as.y + ad.y));
        float v2 = __expf(lrelu(as.z + ad.z));
        float v3 = __expf(lrelu(as.w + ad.w));
        den0 += v0; den1 += v1; den2 += v2; den3 += v3;
        float xk[5] = {x03.x, x03.y, x03.z, x03.w, x4};
#pragma unroll
        for (int k = 0; k < 5; ++k) {
            acc[0][k] = fmaf(v0, xk[k], acc[0][k]);
            acc[1][k] = fmaf(v1, xk[k], acc[1][k]);
            acc[2][k] = fmaf(v2, xk[k], acc[2][k]);
            acc[3][k] = fmaf(v3, xk[k], acc[3][k]);
        }
    }
#pragma unroll
    for (int m = 8; m; m >>= 1) {
        den0 += __shfl_xor(den0, m, 16); den1 += __shfl_xor(den1, m, 16);
        den2 += __shfl_xor(den2, m, 16); den3 += __shfl_xor(den3, m, 16);
#pragma unroll
        for (int h = 0; h < 4; ++h)
#pragma unroll
            for (int k = 0; k < 5; ++k) acc[h][k] += __shfl_xor(acc[h][k], m, 16);
    }
    // expand: lane handles channels c0..c0+7, all in head h = lane>>2
    int c0 = lane * 8;
    int h = lane >> 2;
    float dh = (h == 0) ? den0 : (h == 1) ? den1 : (h == 2) ? den2 : den3;
    float ih = 1.f / dh;
    float ag[5];
#pragma unroll
    for (int k = 0; k < 5; ++k) ag[k] = acc[h][k] * ih;
    float o[8];
#pragma unroll
    for (int j = 0; j < 8; ++j) {
        int c = c0 + j;
        float rr = b1l[c];
#pragma unroll
        for (int k = 0; k < 5; ++k) rr = fmaf(ag[k], Wl[k * 128 + c], rr);
        o[j] = elu1(rr);
    }
    float* op = out1 + (size_t)g * 128 + c0;
    *(float4*)op       = make_float4(o[0], o[1], o[2], o[3]);
    *(float4*)(op + 4) = make_float4(o[4], o[5], o[6], o[7]);
}

// ---------------- layer 2 ----------------

// h2 = out1 @ W2 (128 -> 32) + single-head attention dots
__global__ __launch_bounds__(256) void k_feat2(
    const float* __restrict__ h1b, const float* __restrict__ W2,
    const float* __restrict__ att_s, const float* __restrict__ att_d,
    float* __restrict__ h2, float* __restrict__ a_s, float* __restrict__ a_d, int N) {
    __shared__ float Wl[128 * 32];
    for (int i = threadIdx.x; i < 128 * 32; i += 256) Wl[i] = W2[i];
    __syncthreads();
    int t = blockIdx.x * 256 + threadIdx.x;
    int n = t >> 5, c = t & 31;
    if (n >= N) return;
    const float4* hr4 = (const float4*)(h1b + (size_t)n * 128);
    float acc = 0.f;
#pragma unroll
    for (int k4 = 0; k4 < 32; ++k4) {
        float4 hv = hr4[k4];
        acc = fmaf(hv.x, Wl[(k4 * 4 + 0) * 32 + c], acc);
        acc = fmaf(hv.y, Wl[(k4 * 4 + 1) * 32 + c], acc);
        acc = fmaf(hv.z, Wl[(k4 * 4 + 2) * 32 + c], acc);
        acc = fmaf(hv.w, Wl[(k4 * 4 + 3) * 32 + c], acc);
    }
    h2[(size_t)n * 32 + c] = acc;
    float as = acc * att_s[c], ad = acc * att_d[c];
#pragma unroll
    for (int m = 16; m; m >>= 1) {
        as += __shfl_xor(as, m, 32);
        ad += __shfl_xor(ad, m, 32);
    }
    if (c == 0) { a_s[n] = as; a_d[n] = ad; }
}

// ---------------- layer-2 aggregation + fused MLP head ----------------
// 32-lane group per dst; one exp per edge (lane-owned); 8 independent
// coalesced 128B h2-row loads in flight per inner block.
__global__ __launch_bounds__(256) void k_agg2h(
    const int* __restrict__ off, const int* __restrict__ csr_src,
    const float* __restrict__ a_s, const float* __restrict__ a_d,
    const float* __restrict__ h2, const float* __restrict__ b2,
    const float* __restrict__ Wc1, const float* __restrict__ bc1,
    const float* __restrict__ Wc2, const float* __restrict__ bc2,
    float* __restrict__ out, int N) {
    __shared__ float Wl[512];
    __shared__ float b2l[32], b1l[16], w2l[16];
    for (int i = threadIdx.x; i < 512; i += 256) Wl[i] = Wc1[i];
    if (threadIdx.x < 32) b2l[threadIdx.x] = b2[threadIdx.x];
    if (threadIdx.x < 16) {
        b1l[threadIdx.x] = bc1[threadIdx.x];
        w2l[threadIdx.x] = Wc2[threadIdx.x];
    }
    __syncthreads();
    int g = (blockIdx.x * 256 + threadIdx.x) >> 5;
    int lane = threadIdx.x & 31;
    if (g >= N) return;
    int p0 = off[g], p1 = off[g + 1];
    float ad = a_d[g];
    float acc = 0.f, den = 0.f;
    for (int base = p0; base < p1; base += 32) {
        int rem = p1 - base;
        int s = g;                 // safe index for padded lanes
        float w = 0.f;
        if (lane < rem) {
            s = csr_src[base + lane];           // coalesced
            w = __expf(lrelu(a_s[s] + ad));     // one exp per edge
        }
        den += w;
        int cnt = min(rem, 32);
        int rc = (cnt + 7) & ~7;   // pad to multiple of 8 (w=0 beyond cnt)
        for (int j = 0; j < rc; j += 8) {
#pragma unroll
            for (int jj = 0; jj < 8; ++jj) {
                int   sj = __shfl(s, j + jj, 32);
                float wj = __shfl(w, j + jj, 32);
                acc = fmaf(wj, h2[(size_t)sj * 32 + lane], acc);
            }
        }
    }
#pragma unroll
    for (int m = 16; m; m >>= 1) den += __shfl_xor(den, m, 32);
    float z = elu1(fmaf(acc, 1.f / den, b2l[lane]));
    float y = b1l[lane & 15];
#pragma unroll
    for (int c = 0; c < 32; ++c) {
        float zc = __shfl(z, c, 32);
        y = fmaf(zc, Wl[c * 16 + (lane & 15)], y);
    }
    y = fmaxf(y, 0.f);
    float t = (lane < 16) ? y * w2l[lane] : 0.f;
#pragma unroll
    for (int m = 8; m; m >>= 1) t += __shfl_xor(t, m, 32);
    if (lane == 0) out[g] = t + bc2[0];
}

extern "C" void kernel_launch(void* const* d_in, const int* in_sizes, int n_in,
                              void* d_out, int out_size, void* d_ws, size_t ws_size,
                              hipStream_t stream) {
    const float* x   = (const float*)d_in[0];
    const int*   ei  = (const int*)d_in[1];
    const float* W1  = (const float*)d_in[2];
    const float* as1 = (const float*)d_in[3];
    const float* ad1 = (const float*)d_in[4];
    const float* b1  = (const float*)d_in[5];
    const float* W2  = (const float*)d_in[6];
    const float* as2 = (const float*)d_in[7];
    const float* ad2 = (const float*)d_in[8];
    const float* b2  = (const float*)d_in[9];
    const float* Wc1 = (const float*)d_in[10];
    const float* bc1 = (const float*)d_in[11];
    const float* Wc2 = (const float*)d_in[12];
    const float* bc2 = (const float*)d_in[13];
    float* out = (float*)d_out;

    const int N = out_size;                  // 50000
    const int E = in_sizes[1] / 2;           // 800000
    const int ET = E + N;                    // + self loops
    const int nbuck = (N + 63) >> BSHIFT;    // 782
    const int M = nbuck * SCATB;             // 50048 scan elements
    const int chunk = (ET + SCATB - 1) / SCATB;

    // Workspace layout
    float*    ws    = (float*)d_ws;
    float*    out1  = ws;                               // N*128
    float*    h2    = out1 + (size_t)N * 128;           // N*32
    float*    rec   = h2   + (size_t)N * 32;            // N*16 (packed node record)
    float*    a_s2  = rec  + (size_t)N * 16;            // N
    float*    a_d2  = a_s2 + N;                         // N
    int*      off   = (int*)(a_d2 + N);                 // N+1
    int*      csr_src = off + (N + 2);                  // ET
    int*      Cmat  = csr_src + ET;                     // M
    int*      blkoff = Cmat + M;                        // M+1
    int*      bsum  = blkoff + (M + 2);                 // 256
    unsigned* pairs = (unsigned*)(bsum + 256);          // ET

    auto cdiv = [](long long a, long long b) { return (int)((a + b - 1) / b); };
    const int B = 256;
    const int NB2 = cdiv(M, B);   // 196 <= 256

    // ---- CSR build (count -> scan -> scatter -> bucket sort) ----
    k_cnt<<<SCATB, B, 0, stream>>>(ei, E, ET, chunk, Cmat, nbuck);
    k_scan1<<<NB2, B, 0, stream>>>(Cmat, blkoff, bsum, M);
    k_scan2<<<1, B, 0, stream>>>(bsum, NB2);
    k_scan3<<<NB2, B, 0, stream>>>(blkoff, bsum, off, M, N, ET);
    k_scat<<<SCATB, B, 0, stream>>>(ei, E, ET, chunk, blkoff, pairs, nbuck);
    k_sortB<<<nbuck, B, 0, stream>>>(pairs, blkoff, off, csr_src, N, ET, nbuck);

    // ---- layer 1 (input-space aggregation, fused expand) ----
    k_attn1<<<cdiv(N, B), B, 0, stream>>>(x, W1, as1, ad1, rec, N);
    k_agg1<<<cdiv((long long)N * 16, B), B, 0, stream>>>(off, csr_src, rec, W1, b1, out1, N);

    // ---- layer 2 ----
    k_feat2<<<cdiv((long long)N * 32, B), B, 0, stream>>>(out1, W2, as2, ad2, h2, a_s2, a_d2, N);
    k_agg2h<<<cdiv((long long)N * 32, B), B, 0, stream>>>(off, csr_src, a_s2, a_d2, h2, b2,
                                                          Wc1, bc1, Wc2, bc2, out, N);
}

// Round 9
// 120.278 us; speedup vs baseline: 2.9121x; 1.2986x over previous
//
#include <hip/hip_runtime.h>
#include <hip/hip_fp16.h>

#define NEG_SLOPE 0.2f
#define BSHIFT 6          // bucket = 64 consecutive dst ids
#define SCATB 256         // blocks in count/scatter phases

__device__ __forceinline__ float elu1(float v) { return v > 0.f ? v : expm1f(v); }
__device__ __forceinline__ float lrelu(float v) { return v > 0.f ? v : NEG_SLOPE * v; }

// ---------------- CSR build: exact-offset bucketing (no global atomics) ----------------

__global__ __launch_bounds__(256) void k_cnt(
    const int* __restrict__ ei, int E, int ET, int chunk,
    int* __restrict__ Cmat, int nbuck) {
    __shared__ int hist[784];
    for (int i = threadIdx.x; i < nbuck; i += 256) hist[i] = 0;
    __syncthreads();
    int k = blockIdx.x;
    int e0 = k * chunk, e1 = min(e0 + chunk, ET);
    for (int e = e0 + threadIdx.x; e < e1; e += 256) {
        int d = (e < E) ? ei[E + e] : e - E;
        atomicAdd(&hist[d >> BSHIFT], 1);
    }
    __syncthreads();
    for (int i = threadIdx.x; i < nbuck; i += 256)
        Cmat[i * SCATB + k] = hist[i];
}

__global__ __launch_bounds__(256) void k_scan1(
    const int* __restrict__ Cmat, int* __restrict__ blkoff, int* __restrict__ bsum, int M) {
    __shared__ int ws4[4], wsoff[4];
    int i = blockIdx.x * 256 + threadIdx.x;
    int lane = threadIdx.x & 63, w = threadIdx.x >> 6;
    int v = (i < M) ? Cmat[i] : 0;
    int sc = v;
#pragma unroll
    for (int m = 1; m < 64; m <<= 1) {
        int t = __shfl_up(sc, m, 64);
        if (lane >= m) sc += t;
    }
    if (lane == 63) ws4[w] = sc;
    __syncthreads();
    if (threadIdx.x == 0) {
        int r = 0;
#pragma unroll
        for (int j = 0; j < 4; ++j) { wsoff[j] = r; r += ws4[j]; }
        bsum[blockIdx.x] = r;
    }
    __syncthreads();
    if (i < M) blkoff[i + 1] = sc + wsoff[w];
}

// scan block totals (nb <= 1024), 16-wave block, inclusive in-place
__global__ __launch_bounds__(1024) void k_scan2(int* __restrict__ bsum, int nb) {
    __shared__ int wsum[16];
    int i = threadIdx.x, lane = i & 63, w = i >> 6;
    int v = (i < nb) ? bsum[i] : 0, sc = v;
#pragma unroll
    for (int m = 1; m < 64; m <<= 1) {
        int t = __shfl_up(sc, m, 64);
        if (lane >= m) sc += t;
    }
    if (lane == 63) wsum[w] = sc;
    __syncthreads();
    if (w == 0 && lane < 16) {
        int s2 = wsum[lane];
#pragma unroll
        for (int m = 1; m < 16; m <<= 1) {
            int t = __shfl_up(s2, m, 16);
            if (lane >= m) s2 += t;
        }
        wsum[lane] = s2;
    }
    __syncthreads();
    int carry = (w == 0) ? 0 : wsum[w - 1];
    if (i < nb) bsum[i] = carry + sc;
}

__global__ __launch_bounds__(256) void k_scan3(
    int* __restrict__ blkoff, const int* __restrict__ bsum,
    int* __restrict__ off, int M, int N, int ET) {
    int i = blockIdx.x * 256 + threadIdx.x;
    if (i == 0) { blkoff[0] = 0; off[N] = ET; }
    if (i >= M) return;
    if (blockIdx.x > 0) blkoff[i + 1] += bsum[blockIdx.x - 1];
}

__global__ __launch_bounds__(256) void k_scat(
    const int* __restrict__ ei, int E, int ET, int chunk,
    const int* __restrict__ blkoff, unsigned* __restrict__ pairs, int nbuck) {
    __shared__ int cur[784];
    int k = blockIdx.x;
    for (int i = threadIdx.x; i < nbuck; i += 256)
        cur[i] = blkoff[i * SCATB + k];
    __syncthreads();
    int e0 = k * chunk, e1 = min(e0 + chunk, ET);
    for (int e = e0 + threadIdx.x; e < e1; e += 256) {
        int s, d;
        if (e < E) { s = ei[e]; d = ei[E + e]; } else { s = d = e - E; }
        int p = atomicAdd(&cur[d >> BSHIFT], 1);
        pairs[p] = (unsigned)s | ((unsigned)(d & 63) << 16);   // src < 65536
    }
}

__global__ __launch_bounds__(256) void k_sortB(
    const unsigned* __restrict__ pairs, const int* __restrict__ blkoff,
    int* __restrict__ off, int* __restrict__ csr_src, int N, int ET, int nbuck) {
    __shared__ int hist[64], cur[64];
    int b = blockIdx.x;
    int base = blkoff[b * SCATB];
    int end  = (b + 1 < nbuck) ? blkoff[(b + 1) * SCATB] : ET;
    int cnt = end - base;
    int dstBase = b << BSHIFT;
    if (threadIdx.x < 64) hist[threadIdx.x] = 0;
    __syncthreads();
    for (int i = threadIdx.x; i < cnt; i += 256)
        atomicAdd(&hist[pairs[base + i] >> 16], 1);
    __syncthreads();
    if (threadIdx.x < 64) {
        int v = hist[threadIdx.x], sc = v;
#pragma unroll
        for (int m = 1; m < 64; m <<= 1) {
            int t = __shfl_up(sc, m, 64);
            if (threadIdx.x >= m) sc += t;
        }
        int ex = sc - v;
        cur[threadIdx.x] = ex;
        int d = dstBase + threadIdx.x;
        if (d < N) off[d] = base + ex;
    }
    __syncthreads();
    for (int i = threadIdx.x; i < cnt; i += 256) {
        unsigned pr = pairs[base + i];
        int r = atomicAdd(&cur[pr >> 16], 1);
        csr_src[base + r] = (int)(pr & 0xFFFFu);
    }
}

// ---------------- layer 1 ----------------

// per node: packed 64B record rec[16] = {as4[0:4), x[4:9), pad, ad4[12:16)}
__global__ __launch_bounds__(256) void k_attn1(
    const float* __restrict__ x, const float* __restrict__ W1,
    const float* __restrict__ att_s, const float* __restrict__ att_d,
    float* __restrict__ rec, int N) {
    __shared__ float Ps[5][4], Pd[5][4];
    if (threadIdx.x < 40) {
        int pair = threadIdx.x & 1, idx = threadIdx.x >> 1;
        int k = idx >> 2, h = idx & 3;
        const float* att = pair ? att_d : att_s;
        float r = 0.f;
#pragma unroll
        for (int c = 0; c < 32; ++c) r = fmaf(W1[k * 128 + h * 32 + c], att[h * 32 + c], r);
        if (pair) Pd[k][h] = r; else Ps[k][h] = r;
    }
    __syncthreads();
    int n = blockIdx.x * 256 + threadIdx.x;
    if (n >= N) return;
    float xv[5];
#pragma unroll
    for (int k = 0; k < 5; ++k) xv[k] = x[(size_t)n * 5 + k];
    float s0 = 0, s1 = 0, s2 = 0, s3 = 0, d0 = 0, d1 = 0, d2 = 0, d3 = 0;
#pragma unroll
    for (int k = 0; k < 5; ++k) {
        s0 = fmaf(xv[k], Ps[k][0], s0); s1 = fmaf(xv[k], Ps[k][1], s1);
        s2 = fmaf(xv[k], Ps[k][2], s2); s3 = fmaf(xv[k], Ps[k][3], s3);
        d0 = fmaf(xv[k], Pd[k][0], d0); d1 = fmaf(xv[k], Pd[k][1], d1);
        d2 = fmaf(xv[k], Pd[k][2], d2); d3 = fmaf(xv[k], Pd[k][3], d3);
    }
    float* r = rec + (size_t)n * 16;
    *(float4*)(r)     = make_float4(s0, s1, s2, s3);
    *(float4*)(r + 4) = make_float4(xv[0], xv[1], xv[2], xv[3]);
    r[8] = xv[4];
    *(float4*)(r + 12) = make_float4(d0, d1, d2, d3);
}

// 16-lane group per dst: softmax-weighted aggregation of x (one 64B line/edge)
// + fused expand; out1 stored fp16 (half traffic).
__global__ __launch_bounds__(256) void k_agg1(
    const int* __restrict__ off, const int* __restrict__ csr_src,
    const float* __restrict__ rec, const float* __restrict__ W1,
    const float* __restrict__ b1, __half* __restrict__ out1h, int N) {
    __shared__ float Wl[5 * 128];
    __shared__ float b1l[128];
    for (int i = threadIdx.x; i < 5 * 128; i += 256) Wl[i] = W1[i];
    if (threadIdx.x < 128) b1l[threadIdx.x] = b1[threadIdx.x];
    __syncthreads();
    int g = (blockIdx.x * 256 + threadIdx.x) >> 4;
    int lane = threadIdx.x & 15;
    if (g >= N) return;
    int p0 = off[g], p1 = off[g + 1];
    float4 ad = *(const float4*)(rec + (size_t)g * 16 + 12);
    float den0 = 0, den1 = 0, den2 = 0, den3 = 0;
    float acc[4][5] = {};
    for (int p = p0 + lane; p < p1; p += 16) {
        int s = csr_src[p];
        const float* r = rec + (size_t)s * 16;
        float4 as  = *(const float4*)r;
        float4 x03 = *(const float4*)(r + 4);
        float  x4  = r[8];
        float v0 = __expf(lrelu(as.x + ad.x));
        float v1 = __expf(lrelu(as.y + ad.y));
        float v2 = __expf(lrelu(as.z + ad.z));
        float v3 = __expf(lrelu(as.w + ad.w));
        den0 += v0; den1 += v1; den2 += v2; den3 += v3;
        float xk[5] = {x03.x, x03.y, x03.z, x03.w, x4};
#pragma unroll
        for (int k = 0; k < 5; ++k) {
            acc[0][k] = fmaf(v0, xk[k], acc[0][k]);
            acc[1][k] = fmaf(v1, xk[k], acc[1][k]);
            acc[2][k] = fmaf(v2, xk[k], acc[2][k]);
            acc[3][k] = fmaf(v3, xk[k], acc[3][k]);
        }
    }
#pragma unroll
    for (int m = 8; m; m >>= 1) {
        den0 += __shfl_xor(den0, m, 16); den1 += __shfl_xor(den1, m, 16);
        den2 += __shfl_xor(den2, m, 16); den3 += __shfl_xor(den3, m, 16);
#pragma unroll
        for (int h = 0; h < 4; ++h)
#pragma unroll
            for (int k = 0; k < 5; ++k) acc[h][k] += __shfl_xor(acc[h][k], m, 16);
    }
    int c0 = lane * 8;
    int h = lane >> 2;
    float dh = (h == 0) ? den0 : (h == 1) ? den1 : (h == 2) ? den2 : den3;
    float ih = 1.f / dh;
    float ag[5];
#pragma unroll
    for (int k = 0; k < 5; ++k) ag[k] = acc[h][k] * ih;
    __half2 ph[4];
#pragma unroll
    for (int j = 0; j < 4; ++j) {
        float oa, ob;
        {
            int c = c0 + 2 * j;
            float rr = b1l[c];
#pragma unroll
            for (int k = 0; k < 5; ++k) rr = fmaf(ag[k], Wl[k * 128 + c], rr);
            oa = elu1(rr);
            rr = b1l[c + 1];
#pragma unroll
            for (int k = 0; k < 5; ++k) rr = fmaf(ag[k], Wl[k * 128 + c + 1], rr);
            ob = elu1(rr);
        }
        ph[j] = __floats2half2_rn(oa, ob);
    }
    *(float4*)(out1h + (size_t)g * 128 + c0) = *(float4*)ph;
}

// ---------------- layer 2 ----------------

// h2 = out1 @ W2 (128 -> 32) + single-head attention dots; h2 stored fp16
__global__ __launch_bounds__(256) void k_feat2(
    const __half* __restrict__ out1h, const float* __restrict__ W2,
    const float* __restrict__ att_s, const float* __restrict__ att_d,
    __half* __restrict__ h2h, float* __restrict__ a_s, float* __restrict__ a_d, int N) {
    __shared__ float Wl[128 * 32];
    for (int i = threadIdx.x; i < 128 * 32; i += 256) Wl[i] = W2[i];
    __syncthreads();
    int t = blockIdx.x * 256 + threadIdx.x;
    int n = t >> 5, c = t & 31;
    if (n >= N) return;
    const float4* hr4 = (const float4*)(out1h + (size_t)n * 128);  // 8 halves per float4
    float acc = 0.f;
#pragma unroll
    for (int k4 = 0; k4 < 16; ++k4) {
        float4 q = hr4[k4];
        const __half2* hp = (const __half2*)&q;
#pragma unroll
        for (int m = 0; m < 4; ++m) {
            float2 f = __half22float2(hp[m]);
            acc = fmaf(f.x, Wl[(k4 * 8 + 2 * m) * 32 + c], acc);
            acc = fmaf(f.y, Wl[(k4 * 8 + 2 * m + 1) * 32 + c], acc);
        }
    }
    h2h[(size_t)n * 32 + c] = __float2half_rn(acc);
    float as = acc * att_s[c], ad = acc * att_d[c];
#pragma unroll
    for (int m = 16; m; m >>= 1) {
        as += __shfl_xor(as, m, 32);
        ad += __shfl_xor(ad, m, 32);
    }
    if (c == 0) { a_s[n] = as; a_d[n] = ad; }
}

// ---------------- layer-2 aggregation + fused MLP head ----------------
// 32-lane group per dst; one exp per edge (lane-owned); 8 independent
// coalesced 64B fp16 h2-row loads in flight (h2 = 3.2MB, fits per-XCD L2).
__global__ __launch_bounds__(256) void k_agg2h(
    const int* __restrict__ off, const int* __restrict__ csr_src,
    const float* __restrict__ a_s, const float* __restrict__ a_d,
    const __half* __restrict__ h2h, const float* __restrict__ b2,
    const float* __restrict__ Wc1, const float* __restrict__ bc1,
    const float* __restrict__ Wc2, const float* __restrict__ bc2,
    float* __restrict__ out, int N) {
    __shared__ float Wl[512];
    __shared__ float b2l[32], b1l[16], w2l[16];
    for (int i = threadIdx.x; i < 512; i += 256) Wl[i] = Wc1[i];
    if (threadIdx.x < 32) b2l[threadIdx.x] = b2[threadIdx.x];
    if (threadIdx.x < 16) {
        b1l[threadIdx.x] = bc1[threadIdx.x];
        w2l[threadIdx.x] = Wc2[threadIdx.x];
    }
    __syncthreads();
    int g = (blockIdx.x * 256 + threadIdx.x) >> 5;
    int lane = threadIdx.x & 31;
    if (g >= N) return;
    int p0 = off[g], p1 = off[g + 1];
    float ad = a_d[g];
    float acc = 0.f, den = 0.f;
    for (int base = p0; base < p1; base += 32) {
        int rem = p1 - base;
        int s = g;                 // safe index for padded lanes
        float w = 0.f;
        if (lane < rem) {
            s = csr_src[base + lane];           // coalesced
            w = __expf(lrelu(a_s[s] + ad));     // one exp per edge
        }
        den += w;
        int cnt = min(rem, 32);
        int rc = (cnt + 7) & ~7;   // pad to multiple of 8 (w=0 beyond cnt)
        for (int j = 0; j < rc; j += 8) {
#pragma unroll
            for (int jj = 0; jj < 8; ++jj) {
                int   sj = __shfl(s, j + jj, 32);
                float wj = __shfl(w, j + jj, 32);
                float hv = __half2float(h2h[(size_t)sj * 32 + lane]);
                acc = fmaf(wj, hv, acc);
            }
        }
    }
#pragma unroll
    for (int m = 16; m; m >>= 1) den += __shfl_xor(den, m, 32);
    float z = elu1(fmaf(acc, 1.f / den, b2l[lane]));
    float y = b1l[lane & 15];
#pragma unroll
    for (int c = 0; c < 32; ++c) {
        float zc = __shfl(z, c, 32);
        y = fmaf(zc, Wl[c * 16 + (lane & 15)], y);
    }
    y = fmaxf(y, 0.f);
    float t = (lane < 16) ? y * w2l[lane] : 0.f;
#pragma unroll
    for (int m = 8; m; m >>= 1) t += __shfl_xor(t, m, 32);
    if (lane == 0) out[g] = t + bc2[0];
}

extern "C" void kernel_launch(void* const* d_in, const int* in_sizes, int n_in,
                              void* d_out, int out_size, void* d_ws, size_t ws_size,
                              hipStream_t stream) {
    const float* x   = (const float*)d_in[0];
    const int*   ei  = (const int*)d_in[1];
    const float* W1  = (const float*)d_in[2];
    const float* as1 = (const float*)d_in[3];
    const float* ad1 = (const float*)d_in[4];
    const float* b1  = (const float*)d_in[5];
    const float* W2  = (const float*)d_in[6];
    const float* as2 = (const float*)d_in[7];
    const float* ad2 = (const float*)d_in[8];
    const float* b2  = (const float*)d_in[9];
    const float* Wc1 = (const float*)d_in[10];
    const float* bc1 = (const float*)d_in[11];
    const float* Wc2 = (const float*)d_in[12];
    const float* bc2 = (const float*)d_in[13];
    float* out = (float*)d_out;

    const int N = out_size;                  // 50000
    const int E = in_sizes[1] / 2;           // 800000
    const int ET = E + N;                    // + self loops
    const int nbuck = (N + 63) >> BSHIFT;    // 782
    const int M = nbuck * SCATB;             // 200192 scan elements
    const int chunk = (ET + SCATB - 1) / SCATB;

    // Workspace layout
    float*    ws    = (float*)d_ws;
    __half*   out1h = (__half*)ws;                      // N*128 halves (N*64 floats)
    __half*   h2h   = (__half*)(ws + (size_t)N * 64);   // N*32 halves (N*16 floats)
    float*    rec   = ws + (size_t)N * 80;              // N*16
    float*    a_s2  = rec  + (size_t)N * 16;            // N
    float*    a_d2  = a_s2 + N;                         // N
    int*      off   = (int*)(a_d2 + N);                 // N+1
    int*      csr_src = off + (N + 2);                  // ET
    int*      Cmat  = csr_src + ET;                     // M
    int*      blkoff = Cmat + M;                        // M+2
    int*      bsum  = blkoff + (M + 2);                 // 1024
    unsigned* pairs = (unsigned*)(bsum + 1024);         // ET

    auto cdiv = [](long long a, long long b) { return (int)((a + b - 1) / b); };
    const int B = 256;
    const int NB2 = cdiv(M, B);   // 782 <= 1024

    // ---- CSR build (count -> scan -> scatter -> bucket sort) ----
    k_cnt<<<SCATB, B, 0, stream>>>(ei, E, ET, chunk, Cmat, nbuck);
    k_scan1<<<NB2, B, 0, stream>>>(Cmat, blkoff, bsum, M);
    k_scan2<<<1, 1024, 0, stream>>>(bsum, NB2);
    k_scan3<<<NB2, B, 0, stream>>>(blkoff, bsum, off, M, N, ET);
    k_scat<<<SCATB, B, 0, stream>>>(ei, E, ET, chunk, blkoff, pairs, nbuck);
    k_sortB<<<nbuck, B, 0, stream>>>(pairs, blkoff, off, csr_src, N, ET, nbuck);

    // ---- layer 1 (input-space aggregation, fused expand) ----
    k_attn1<<<cdiv(N, B), B, 0, stream>>>(x, W1, as1, ad1, rec, N);
    k_agg1<<<cdiv((long long)N * 16, B), B, 0, stream>>>(off, csr_src, rec, W1, b1, out1h, N);

    // ---- layer 2 ----
    k_feat2<<<cdiv((long long)N * 32, B), B, 0, stream>>>(out1h, W2, as2, ad2, h2h, a_s2, a_d2, N);
    k_agg2h<<<cdiv((long long)N * 32, B), B, 0, stream>>>(off, csr_src, a_s2, a_d2, h2h, b2,
                                                          Wc1, bc1, Wc2, bc2, out, N);
}

// Round 10
// 117.582 us; speedup vs baseline: 2.9789x; 1.0229x over previous
//
#include <hip/hip_runtime.h>
#include <hip/hip_fp16.h>

#define NEG_SLOPE 0.2f
#define BSHIFT 6          // bucket = 64 consecutive dst ids
#define SCATB 256         // blocks in count/scatter phases

__device__ __forceinline__ float elu1(float v) { return v > 0.f ? v : expm1f(v); }
__device__ __forceinline__ float lrelu(float v) { return v > 0.f ? v : NEG_SLOPE * v; }

// global exclusive offset of scan element j, given scan1 partials + scanned block sums
__device__ __forceinline__ int ge_off(const int* __restrict__ blkoff,
                                      const int* __restrict__ bsum2, int j) {
    if (j == 0) return 0;
    int b = (j - 1) >> 8;            // scan1 block of element j-1 (256/block)
    int v = blkoff[j];
    if (b >= 1) v += bsum2[b - 1];
    return v;
}

// ---------------- CSR build: exact-offset bucketing (no global atomics) ----------------

// Fused: blocks [0,SCATB) do the bucket histogram; blocks [SCATB, SCATB+nAttn) do attn1.
__global__ __launch_bounds__(256) void k_cnt_attn(
    const int* __restrict__ ei, int E, int ET, int chunk,
    int* __restrict__ Cmat, int nbuck,
    const float* __restrict__ x, const float* __restrict__ W1,
    const float* __restrict__ att_s, const float* __restrict__ att_d,
    float* __restrict__ rec, int N) {
    __shared__ int hist[784];
    __shared__ float Ps[5][4], Pd[5][4];
    if (blockIdx.x < SCATB) {
        for (int i = threadIdx.x; i < nbuck; i += 256) hist[i] = 0;
        __syncthreads();
        int k = blockIdx.x;
        int e0 = k * chunk, e1 = min(e0 + chunk, ET);
        for (int e = e0 + threadIdx.x; e < e1; e += 256) {
            int d = (e < E) ? ei[E + e] : e - E;
            atomicAdd(&hist[d >> BSHIFT], 1);
        }
        __syncthreads();
        for (int i = threadIdx.x; i < nbuck; i += 256)
            Cmat[i * SCATB + k] = hist[i];
    } else {
        // ---- attn1: packed 64B record rec[16] = {as4, x[0:5), pad, ad4} ----
        if (threadIdx.x < 40) {
            int pair = threadIdx.x & 1, idx = threadIdx.x >> 1;
            int k = idx >> 2, h = idx & 3;
            const float* att = pair ? att_d : att_s;
            float r = 0.f;
#pragma unroll
            for (int c = 0; c < 32; ++c) r = fmaf(W1[k * 128 + h * 32 + c], att[h * 32 + c], r);
            if (pair) Pd[k][h] = r; else Ps[k][h] = r;
        }
        __syncthreads();
        int n = (blockIdx.x - SCATB) * 256 + threadIdx.x;
        if (n >= N) return;
        float xv[5];
#pragma unroll
        for (int k = 0; k < 5; ++k) xv[k] = x[(size_t)n * 5 + k];
        float s0 = 0, s1 = 0, s2 = 0, s3 = 0, d0 = 0, d1 = 0, d2 = 0, d3 = 0;
#pragma unroll
        for (int k = 0; k < 5; ++k) {
            s0 = fmaf(xv[k], Ps[k][0], s0); s1 = fmaf(xv[k], Ps[k][1], s1);
            s2 = fmaf(xv[k], Ps[k][2], s2); s3 = fmaf(xv[k], Ps[k][3], s3);
            d0 = fmaf(xv[k], Pd[k][0], d0); d1 = fmaf(xv[k], Pd[k][1], d1);
            d2 = fmaf(xv[k], Pd[k][2], d2); d3 = fmaf(xv[k], Pd[k][3], d3);
        }
        float* r = rec + (size_t)n * 16;
        *(float4*)(r)      = make_float4(s0, s1, s2, s3);
        *(float4*)(r + 4)  = make_float4(xv[0], xv[1], xv[2], xv[3]);
        r[8] = xv[4];
        *(float4*)(r + 12) = make_float4(d0, d1, d2, d3);
    }
}

__global__ __launch_bounds__(256) void k_scan1(
    const int* __restrict__ Cmat, int* __restrict__ blkoff, int* __restrict__ bsum, int M) {
    __shared__ int ws4[4], wsoff[4];
    int i = blockIdx.x * 256 + threadIdx.x;
    int lane = threadIdx.x & 63, w = threadIdx.x >> 6;
    int v = (i < M) ? Cmat[i] : 0;
    int sc = v;
#pragma unroll
    for (int m = 1; m < 64; m <<= 1) {
        int t = __shfl_up(sc, m, 64);
        if (lane >= m) sc += t;
    }
    if (lane == 63) ws4[w] = sc;
    __syncthreads();
    if (threadIdx.x == 0) {
        int r = 0;
#pragma unroll
        for (int j = 0; j < 4; ++j) { wsoff[j] = r; r += ws4[j]; }
        bsum[blockIdx.x] = r;
    }
    __syncthreads();
    if (i < M) blkoff[i + 1] = sc + wsoff[w];
}

// scan block totals (nb <= 1024), 16-wave block, inclusive in-place; also off[N]=ET
__global__ __launch_bounds__(1024) void k_scan2(
    int* __restrict__ bsum, int nb, int* __restrict__ off, int N, int ET) {
    __shared__ int wsum[16];
    int i = threadIdx.x, lane = i & 63, w = i >> 6;
    if (i == 0) off[N] = ET;
    int v = (i < nb) ? bsum[i] : 0, sc = v;
#pragma unroll
    for (int m = 1; m < 64; m <<= 1) {
        int t = __shfl_up(sc, m, 64);
        if (lane >= m) sc += t;
    }
    if (lane == 63) wsum[w] = sc;
    __syncthreads();
    if (w == 0 && lane < 16) {
        int s2 = wsum[lane];
#pragma unroll
        for (int m = 1; m < 16; m <<= 1) {
            int t = __shfl_up(s2, m, 16);
            if (lane >= m) s2 += t;
        }
        wsum[lane] = s2;
    }
    __syncthreads();
    int carry = (w == 0) ? 0 : wsum[w - 1];
    if (i < nb) bsum[i] = carry + sc;
}

__global__ __launch_bounds__(256) void k_scat(
    const int* __restrict__ ei, int E, int ET, int chunk,
    const int* __restrict__ blkoff, const int* __restrict__ bsum2,
    unsigned* __restrict__ pairs, int nbuck) {
    __shared__ int cur[784];
    int k = blockIdx.x;
    for (int i = threadIdx.x; i < nbuck; i += 256)
        cur[i] = ge_off(blkoff, bsum2, i * SCATB + k);
    __syncthreads();
    int e0 = k * chunk, e1 = min(e0 + chunk, ET);
    for (int e = e0 + threadIdx.x; e < e1; e += 256) {
        int s, d;
        if (e < E) { s = ei[e]; d = ei[E + e]; } else { s = d = e - E; }
        int p = atomicAdd(&cur[d >> BSHIFT], 1);
        pairs[p] = (unsigned)s | ((unsigned)(d & 63) << 16);   // src < 65536
    }
}

// per-bucket LDS counting sort, single pass over pairs (LDS-staged)
__global__ __launch_bounds__(256) void k_sortB(
    const unsigned* __restrict__ pairs, const int* __restrict__ blkoff,
    const int* __restrict__ bsum2, int* __restrict__ off,
    int* __restrict__ csr_src, int N, int ET, int nbuck) {
    __shared__ int hist[64], cur[64];
    __shared__ unsigned pl[1536];
    int b = blockIdx.x;
    int base = ge_off(blkoff, bsum2, b * SCATB);
    int end  = (b + 1 < nbuck) ? ge_off(blkoff, bsum2, (b + 1) * SCATB) : ET;
    int cnt = end - base;
    int stg = min(cnt, 1536);
    int dstBase = b << BSHIFT;
    if (threadIdx.x < 64) hist[threadIdx.x] = 0;
    for (int i = threadIdx.x; i < stg; i += 256) pl[i] = pairs[base + i];
    __syncthreads();
    for (int i = threadIdx.x; i < cnt; i += 256) {
        unsigned pr = (i < stg) ? pl[i] : pairs[base + i];
        atomicAdd(&hist[pr >> 16], 1);
    }
    __syncthreads();
    if (threadIdx.x < 64) {
        int v = hist[threadIdx.x], sc = v;
#pragma unroll
        for (int m = 1; m < 64; m <<= 1) {
            int t = __shfl_up(sc, m, 64);
            if (threadIdx.x >= m) sc += t;
        }
        int ex = sc - v;
        cur[threadIdx.x] = ex;
        int d = dstBase + threadIdx.x;
        if (d < N) off[d] = base + ex;
    }
    __syncthreads();
    for (int i = threadIdx.x; i < cnt; i += 256) {
        unsigned pr = (i < stg) ? pl[i] : pairs[base + i];
        int r = atomicAdd(&cur[pr >> 16], 1);
        csr_src[base + r] = (int)(pr & 0xFFFFu);
    }
}

// ---------------- layer 1 ----------------

// 16-lane group per dst: softmax-weighted aggregation of x (one 64B line/edge)
// + fused expand; out1 stored fp16.
__global__ __launch_bounds__(256) void k_agg1(
    const int* __restrict__ off, const int* __restrict__ csr_src,
    const float* __restrict__ rec, const float* __restrict__ W1,
    const float* __restrict__ b1, __half* __restrict__ out1h, int N) {
    __shared__ float Wl[5 * 128];
    __shared__ float b1l[128];
    for (int i = threadIdx.x; i < 5 * 128; i += 256) Wl[i] = W1[i];
    if (threadIdx.x < 128) b1l[threadIdx.x] = b1[threadIdx.x];
    __syncthreads();
    int g = (blockIdx.x * 256 + threadIdx.x) >> 4;
    int lane = threadIdx.x & 15;
    if (g >= N) return;
    int p0 = off[g], p1 = off[g + 1];
    float4 ad = *(const float4*)(rec + (size_t)g * 16 + 12);
    float den0 = 0, den1 = 0, den2 = 0, den3 = 0;
    float acc[4][5] = {};
    for (int p = p0 + lane; p < p1; p += 16) {
        int s = csr_src[p];
        const float* r = rec + (size_t)s * 16;
        float4 as  = *(const float4*)r;
        float4 x03 = *(const float4*)(r + 4);
        float  x4  = r[8];
        float v0 = __expf(lrelu(as.x + ad.x));
        float v1 = __expf(lrelu(as.y + ad.y));
        float v2 = __expf(lrelu(as.z + ad.z));
        float v3 = __expf(lrelu(as.w + ad.w));
        den0 += v0; den1 += v1; den2 += v2; den3 += v3;
        float xk[5] = {x03.x, x03.y, x03.z, x03.w, x4};
#pragma unroll
        for (int k = 0; k < 5; ++k) {
            acc[0][k] = fmaf(v0, xk[k], acc[0][k]);
            acc[1][k] = fmaf(v1, xk[k], acc[1][k]);
            acc[2][k] = fmaf(v2, xk[k], acc[2][k]);
            acc[3][k] = fmaf(v3, xk[k], acc[3][k]);
        }
    }
#pragma unroll
    for (int m = 8; m; m >>= 1) {
        den0 += __shfl_xor(den0, m, 16); den1 += __shfl_xor(den1, m, 16);
        den2 += __shfl_xor(den2, m, 16); den3 += __shfl_xor(den3, m, 16);
#pragma unroll
        for (int h = 0; h < 4; ++h)
#pragma unroll
            for (int k = 0; k < 5; ++k) acc[h][k] += __shfl_xor(acc[h][k], m, 16);
    }
    int c0 = lane * 8;
    int h = lane >> 2;
    float dh = (h == 0) ? den0 : (h == 1) ? den1 : (h == 2) ? den2 : den3;
    float ih = 1.f / dh;
    float ag[5];
#pragma unroll
    for (int k = 0; k < 5; ++k) ag[k] = acc[h][k] * ih;
    __half2 ph[4];
#pragma unroll
    for (int j = 0; j < 4; ++j) {
        int c = c0 + 2 * j;
        float rr = b1l[c];
#pragma unroll
        for (int k = 0; k < 5; ++k) rr = fmaf(ag[k], Wl[k * 128 + c], rr);
        float oa = elu1(rr);
        rr = b1l[c + 1];
#pragma unroll
        for (int k = 0; k < 5; ++k) rr = fmaf(ag[k], Wl[k * 128 + c + 1], rr);
        float ob = elu1(rr);
        ph[j] = __floats2half2_rn(oa, ob);
    }
    *(float4*)(out1h + (size_t)g * 128 + c0) = *(float4*)ph;
}

// ---------------- layer 2 ----------------

// h2 = out1 @ W2 (128 -> 32) + single-head attention dots; h2 stored fp16
__global__ __launch_bounds__(256) void k_feat2(
    const __half* __restrict__ out1h, const float* __restrict__ W2,
    const float* __restrict__ att_s, const float* __restrict__ att_d,
    __half* __restrict__ h2h, float* __restrict__ a_s, float* __restrict__ a_d, int N) {
    __shared__ float Wl[128 * 32];
    for (int i = threadIdx.x; i < 128 * 32; i += 256) Wl[i] = W2[i];
    __syncthreads();
    int t = blockIdx.x * 256 + threadIdx.x;
    int n = t >> 5, c = t & 31;
    if (n >= N) return;
    const float4* hr4 = (const float4*)(out1h + (size_t)n * 128);  // 8 halves per float4
    float acc = 0.f;
#pragma unroll
    for (int k4 = 0; k4 < 16; ++k4) {
        float4 q = hr4[k4];
        const __half2* hp = (const __half2*)&q;
#pragma unroll
        for (int m = 0; m < 4; ++m) {
            float2 f = __half22float2(hp[m]);
            acc = fmaf(f.x, Wl[(k4 * 8 + 2 * m) * 32 + c], acc);
            acc = fmaf(f.y, Wl[(k4 * 8 + 2 * m + 1) * 32 + c], acc);
        }
    }
    h2h[(size_t)n * 32 + c] = __float2half_rn(acc);
    float as = acc * att_s[c], ad = acc * att_d[c];
#pragma unroll
    for (int m = 16; m; m >>= 1) {
        as += __shfl_xor(as, m, 32);
        ad += __shfl_xor(ad, m, 32);
    }
    if (c == 0) { a_s[n] = as; a_d[n] = ad; }
}

// ---------------- layer-2 aggregation + fused MLP head ----------------
__global__ __launch_bounds__(256) void k_agg2h(
    const int* __restrict__ off, const int* __restrict__ csr_src,
    const float* __restrict__ a_s, const float* __restrict__ a_d,
    const __half* __restrict__ h2h, const float* __restrict__ b2,
    const float* __restrict__ Wc1, const float* __restrict__ bc1,
    const float* __restrict__ Wc2, const float* __restrict__ bc2,
    float* __restrict__ out, int N) {
    __shared__ float Wl[512];
    __shared__ float b2l[32], b1l[16], w2l[16];
    for (int i = threadIdx.x; i < 512; i += 256) Wl[i] = Wc1[i];
    if (threadIdx.x < 32) b2l[threadIdx.x] = b2[threadIdx.x];
    if (threadIdx.x < 16) {
        b1l[threadIdx.x] = bc1[threadIdx.x];
        w2l[threadIdx.x] = Wc2[threadIdx.x];
    }
    __syncthreads();
    int g = (blockIdx.x * 256 + threadIdx.x) >> 5;
    int lane = threadIdx.x & 31;
    if (g >= N) return;
    int p0 = off[g], p1 = off[g + 1];
    float ad = a_d[g];
    float acc = 0.f, den = 0.f;
    for (int base = p0; base < p1; base += 32) {
        int rem = p1 - base;
        int s = g;                 // safe index for padded lanes
        float w = 0.f;
        if (lane < rem) {
            s = csr_src[base + lane];           // coalesced
            w = __expf(lrelu(a_s[s] + ad));     // one exp per edge
        }
        den += w;
        int cnt = min(rem, 32);
        int rc = (cnt + 7) & ~7;   // pad to multiple of 8 (w=0 beyond cnt)
        for (int j = 0; j < rc; j += 8) {
#pragma unroll
            for (int jj = 0; jj < 8; ++jj) {
                int   sj = __shfl(s, j + jj, 32);
                float wj = __shfl(w, j + jj, 32);
                float hv = __half2float(h2h[(size_t)sj * 32 + lane]);
                acc = fmaf(wj, hv, acc);
            }
        }
    }
#pragma unroll
    for (int m = 16; m; m >>= 1) den += __shfl_xor(den, m, 32);
    float z = elu1(fmaf(acc, 1.f / den, b2l[lane]));
    float y = b1l[lane & 15];
#pragma unroll
    for (int c = 0; c < 32; ++c) {
        float zc = __shfl(z, c, 32);
        y = fmaf(zc, Wl[c * 16 + (lane & 15)], y);
    }
    y = fmaxf(y, 0.f);
    float t = (lane < 16) ? y * w2l[lane] : 0.f;
#pragma unroll
    for (int m = 8; m; m >>= 1) t += __shfl_xor(t, m, 32);
    if (lane == 0) out[g] = t + bc2[0];
}

extern "C" void kernel_launch(void* const* d_in, const int* in_sizes, int n_in,
                              void* d_out, int out_size, void* d_ws, size_t ws_size,
                              hipStream_t stream) {
    const float* x   = (const float*)d_in[0];
    const int*   ei  = (const int*)d_in[1];
    const float* W1  = (const float*)d_in[2];
    const float* as1 = (const float*)d_in[3];
    const float* ad1 = (const float*)d_in[4];
    const float* b1  = (const float*)d_in[5];
    const float* W2  = (const float*)d_in[6];
    const float* as2 = (const float*)d_in[7];
    const float* ad2 = (const float*)d_in[8];
    const float* b2  = (const float*)d_in[9];
    const float* Wc1 = (const float*)d_in[10];
    const float* bc1 = (const float*)d_in[11];
    const float* Wc2 = (const float*)d_in[12];
    const float* bc2 = (const float*)d_in[13];
    float* out = (float*)d_out;

    const int N = out_size;                  // 50000
    const int E = in_sizes[1] / 2;           // 800000
    const int ET = E + N;                    // + self loops
    const int nbuck = (N + 63) >> BSHIFT;    // 782
    const int M = nbuck * SCATB;             // 200192 scan elements
    const int chunk = (ET + SCATB - 1) / SCATB;

    // Workspace layout
    float*    ws    = (float*)d_ws;
    __half*   out1h = (__half*)ws;                      // N*128 halves (N*64 floats)
    __half*   h2h   = (__half*)(ws + (size_t)N * 64);   // N*32 halves (N*16 floats)
    float*    rec   = ws + (size_t)N * 80;              // N*16
    float*    a_s2  = rec  + (size_t)N * 16;            // N
    float*    a_d2  = a_s2 + N;                         // N
    int*      off   = (int*)(a_d2 + N);                 // N+1
    int*      csr_src = off + (N + 2);                  // ET
    int*      Cmat  = csr_src + ET;                     // M
    int*      blkoff = Cmat + M;                        // M+2
    int*      bsum  = blkoff + (M + 2);                 // 1024
    unsigned* pairs = (unsigned*)(bsum + 1024);         // ET

    auto cdiv = [](long long a, long long b) { return (int)((a + b - 1) / b); };
    const int B = 256;
    const int NB2 = cdiv(M, B);          // 782 <= 1024
    const int nAttn = cdiv(N, B);        // 196

    // ---- CSR build (count+attn1 -> scan -> scatter -> bucket sort) ----
    k_cnt_attn<<<SCATB + nAttn, B, 0, stream>>>(ei, E, ET, chunk, Cmat, nbuck,
                                                x, W1, as1, ad1, rec, N);
    k_scan1<<<NB2, B, 0, stream>>>(Cmat, blkoff, bsum, M);
    k_scan2<<<1, 1024, 0, stream>>>(bsum, NB2, off, N, ET);
    k_scat<<<SCATB, B, 0, stream>>>(ei, E, ET, chunk, blkoff, bsum, pairs, nbuck);
    k_sortB<<<nbuck, B, 0, stream>>>(pairs, blkoff, bsum, off, csr_src, N, ET, nbuck);

    // ---- layer 1 (input-space aggregation, fused expand) ----
    k_agg1<<<cdiv((long long)N * 16, B), B, 0, stream>>>(off, csr_src, rec, W1, b1, out1h, N);

    // ---- layer 2 ----
    k_feat2<<<cdiv((long long)N * 32, B), B, 0, stream>>>(out1h, W2, as2, ad2, h2h, a_s2, a_d2, N);
    k_agg2h<<<cdiv((long long)N * 32, B), B, 0, stream>>>(off, csr_src, a_s2, a_d2, h2h, b2,
                                                          Wc1, bc1, Wc2, bc2, out, N);
}